// Round 15
// baseline (377.678 us; speedup 1.0000x reference)
//
#include <hip/hip_runtime.h>
#include <hip/hip_fp16.h>

#define EPS 1e-15f
#define BKT_SHIFT 7
#define BKT_SIZE 128
#define NBKT_MAX 512

typedef _Float16 v8h __attribute__((ext_vector_type(8)));
typedef float v4f __attribute__((ext_vector_type(4)));
typedef float v2f __attribute__((ext_vector_type(2)));

#if __has_builtin(__builtin_amdgcn_cvt_pk_f32_fp8) && __has_builtin(__builtin_amdgcn_cvt_pk_fp8_f32)
#define FP8_HW 1
#else
#define FP8_HW 0
#endif

// ---------------------------------------------------------------------------
// fp8 helpers (encode in gemm1, decode in agg1 — matched paths)
// ---------------------------------------------------------------------------
__device__ __forceinline__ unsigned char f32_to_fp8(float v) {
#if FP8_HW
    int r = __builtin_amdgcn_cvt_pk_fp8_f32(v, v, 0, false);
    return (unsigned char)(r & 0xFF);
#else
    __half h = __float2half(v);
    unsigned short u; __builtin_memcpy(&u, &h, 2);
    int s = (u >> 15) << 7;
    int a = (u & 0x7FFF) + 0x40;
    if (a < (9 << 10)) return (unsigned char)s;
    int t = (a >> 7) - 64;
    if (t > 126) t = 126;
    return (unsigned char)(s | t);
#endif
}

__device__ __forceinline__ float2 fp8x2_to_f32(unsigned short w) {
#if FP8_HW
    v2f r = __builtin_amdgcn_cvt_pk_f32_fp8((int)w, false);
    return make_float2(r.x, r.y);
#else
    int b0 = w & 0xFF, b1 = w >> 8;
    unsigned short h0 = (unsigned short)((((b0 & 0x7F) + 64) << 7) | ((b0 & 0x80) << 8));
    unsigned short h1 = (unsigned short)((((b1 & 0x7F) + 64) << 7) | ((b1 & 0x80) << 8));
    __half x0, x1;
    __builtin_memcpy(&x0, &h0, 2);
    __builtin_memcpy(&x1, &h1, 2);
    return make_float2(__half2float(x0), __half2float(x1));
#endif
}

// ---------------------------------------------------------------------------
// Helpers
// ---------------------------------------------------------------------------
__device__ __forceinline__ int load_idx(const int* __restrict__ ei, int is64, int pos) {
    return is64 ? ei[(size_t)2 * pos] : ei[pos];
}

__device__ __forceinline__ int h2_as_int(__half2 h) {
    int w; __builtin_memcpy(&w, &h, 4); return w;
}
__device__ __forceinline__ __half2 int_as_h2(int w) {
    __half2 h; __builtin_memcpy(&h, &w, 4); return h;
}

// Detect int64 vs int32 edge_index; ALSO zeroes bcnt.
__global__ void detect_kernel(const int* __restrict__ ei, int* __restrict__ flag,
                              int* __restrict__ bcnt, int nbkt) {
    __shared__ int any_odd;
    if (threadIdx.x == 0) any_odd = 0;
    __syncthreads();
    for (int u = threadIdx.x; u < nbkt; u += 256) bcnt[u] = 0;
    if (ei[2 * threadIdx.x + 1] != 0) atomicOr(&any_odd, 1);
    __syncthreads();
    if (threadIdx.x == 0) *flag = any_odd ? 0 : 1;
}

// Bucket histogram: LDS-aggregated, 4096 edges/block.
__global__ __launch_bounds__(256) void bhist_kernel(
    const int* __restrict__ ei, const int* __restrict__ flag,
    int* __restrict__ bcnt, int E, int nbkt) {
    __shared__ int cnt[NBKT_MAX];
    int t = threadIdx.x;
    for (int u = t; u < nbkt; u += 256) cnt[u] = 0;
    __syncthreads();
    int is64 = *flag;
    int e0 = blockIdx.x * 4096;
#pragma unroll
    for (int i = 0; i < 16; ++i) {
        int e = e0 + i * 256 + t;
        if (e < E) atomicAdd(&cnt[load_idx(ei, is64, E + e) >> BKT_SHIFT], 1);
    }
    __syncthreads();
    for (int u = t; u < nbkt; u += 256)
        if (cnt[u]) atomicAdd(&bcnt[u], cnt[u]);
}

// Exclusive scan over bcnt[nbkt] (nbkt <= 512); also bbase[nbkt]=E, rowptr[N]=E.
__global__ void bscan_kernel(const int* __restrict__ bcnt, int* __restrict__ bbase,
                             int* __restrict__ bcursor, int* __restrict__ rowptrN,
                             int nbkt, int E) {
    __shared__ int s[512];
    int t = threadIdx.x;
    int v = (t < nbkt) ? bcnt[t] : 0;
    s[t] = v;
    __syncthreads();
    for (int o = 1; o < 512; o <<= 1) {
        int u = (t >= o) ? s[t - o] : 0;
        __syncthreads();
        s[t] += u;
        __syncthreads();
    }
    if (t < nbkt) { int ex = s[t] - v; bbase[t] = ex; bcursor[t] = ex; }
    if (t == 0) { bbase[nbkt] = E; *rowptrN = E; }
}

// ---------------------------------------------------------------------------
// Pass 1: bucket multisplit, 8192 edges per 1024-thread block, two-phase.
// ---------------------------------------------------------------------------
__global__ __launch_bounds__(1024) void pass1_kernel(
    const int* __restrict__ ei, const int* __restrict__ flag,
    const float2* __restrict__ ea, int* __restrict__ bcursor,
    int4* __restrict__ staging, int E, int nbkt) {
    __shared__ int lcnt[NBKT_MAX];
    __shared__ int lcur[NBKT_MAX];
    int t = threadIdx.x;
    if (t < nbkt) lcnt[t] = 0;
    __syncthreads();
    int is64 = *flag;
    int e0 = blockIdx.x * 8192;
    int eend = min(e0 + 8192, E);

    for (int e = e0 + t; e < eend; e += 1024)
        atomicAdd(&lcnt[load_idx(ei, is64, E + e) >> BKT_SHIFT], 1);
    __syncthreads();

    if (t < nbkt) {
        int c = lcnt[t];
        lcur[t] = c ? atomicAdd(&bcursor[t], c) : 0;
    }
    __syncthreads();

    for (int e = e0 + t; e < eend; e += 1024) {
        int src = load_idx(ei, is64, e);
        int dst = load_idx(ei, is64, E + e);
        float2 a = ea[e];
        int pos = atomicAdd(&lcur[dst >> BKT_SHIFT], 1);
        staging[pos] = make_int4(src, dst,
                                 __float_as_int(a.x), __float_as_int(a.y));
    }
}

// ---------------------------------------------------------------------------
// Pass 2: one block per bucket. Derives per-node rowptr; places records.
//   rec.x = src | (dl << 24)  (dl = dst & 127; src < 2^24)
// ---------------------------------------------------------------------------
__global__ __launch_bounds__(256) void pass2_kernel(
    const int4* __restrict__ staging, const int* __restrict__ bbase,
    const float* __restrict__ mu1, const float* __restrict__ sg1,
    const float* __restrict__ mu2, const float* __restrict__ sg2,
    int4* __restrict__ rec, int* __restrict__ rowptr, int N) {
    __shared__ int lcnt[BKT_SIZE];
    __shared__ int ssc[BKT_SIZE];
    __shared__ int lcur[BKT_SIZE];
    int b = blockIdx.x;
    int node0 = b << BKT_SHIFT;
    int t = threadIdx.x;
    int beg = bbase[b], end = bbase[b + 1];

    if (t < BKT_SIZE) lcnt[t] = 0;
    __syncthreads();
    for (int j = beg + t; j < end; j += 256)
        atomicAdd(&lcnt[staging[j].y & (BKT_SIZE - 1)], 1);
    __syncthreads();
    int v = (t < BKT_SIZE) ? lcnt[t] : 0;
    if (t < BKT_SIZE) ssc[t] = v;
    __syncthreads();
    for (int o = 1; o < BKT_SIZE; o <<= 1) {
        int u = (t < BKT_SIZE && t >= o) ? ssc[t - o] : 0;
        __syncthreads();
        if (t < BKT_SIZE) ssc[t] += u;
        __syncthreads();
    }
    if (t < BKT_SIZE) {
        int excl = beg + ssc[t] - v;
        lcur[t] = excl;
        if (node0 + t < N) rowptr[node0 + t] = excl;
    }
    __syncthreads();

    float m1x[3], m1y[3], i1x[3], i1y[3], m2x[3], m2y[3], i2x[3], i2y[3];
#pragma unroll
    for (int k = 0; k < 3; ++k) {
        m1x[k] = mu1[2 * k]; m1y[k] = mu1[2 * k + 1];
        float s0 = sg1[2 * k], s1 = sg1[2 * k + 1];
        i1x[k] = -0.5f / (EPS + s0 * s0); i1y[k] = -0.5f / (EPS + s1 * s1);
        m2x[k] = mu2[2 * k]; m2y[k] = mu2[2 * k + 1];
        s0 = sg2[2 * k]; s1 = sg2[2 * k + 1];
        i2x[k] = -0.5f / (EPS + s0 * s0); i2y[k] = -0.5f / (EPS + s1 * s1);
    }

    for (int j = beg + t; j < end; j += 256) {
        int4 p = staging[j];
        float ax = __int_as_float(p.z), ay = __int_as_float(p.w);
        float g1v[3], g2v[3];
#pragma unroll
        for (int k = 0; k < 3; ++k) {
            float d0 = ax - m1x[k], d1 = ay - m1y[k];
            g1v[k] = __expf(d0 * d0 * i1x[k] + d1 * d1 * i1y[k]);
            d0 = ax - m2x[k]; d1 = ay - m2y[k];
            g2v[k] = __expf(d0 * d0 * i2x[k] + d1 * d1 * i2y[k]);
        }
        int dl = p.y & (BKT_SIZE - 1);
        int pos = atomicAdd(&lcur[dl], 1);
        int4 r;
        r.x = p.x | (dl << 24);
        r.y = h2_as_int(__floats2half2_rn(g1v[0], g1v[1]));
        r.z = h2_as_int(__floats2half2_rn(g1v[2], g2v[0]));
        r.w = h2_as_int(__floats2half2_rn(g2v[1], g2v[2]));
        rec[pos] = r;
    }
}

// ---------------------------------------------------------------------------
// Bprep: fragment-ordered fp16 copy of W = [g1 | r1]  (128 x 256).
// ---------------------------------------------------------------------------
__global__ void bprep_kernel(const float* __restrict__ g1, const float* __restrict__ r1,
                             __half* __restrict__ Bprep) {
    int gid = blockIdx.x * 256 + threadIdx.x;   // 32768 total
    if (gid >= 32768) return;
    int fi = gid >> 9;
    int lane = (gid >> 3) & 63;
    int i = gid & 7;
    int ks = fi & 3, cb = fi >> 2;
    int k = ks * 32 + (lane >> 4) * 8 + i;
    int c = cb * 16 + (lane & 15);
    float v = (c < 192) ? g1[k * 192 + c] : r1[k * 64 + (c - 192)];
    Bprep[gid] = __float2half(v);
}

// ---------------------------------------------------------------------------
// Layer-1 GEMM via MFMA f16: x [M,128] fp32 -> hw1k fp8 [M,192] + hw1r fp16 [M,64].
// ---------------------------------------------------------------------------
__global__ __launch_bounds__(256) void gemm1_mfma(
    const float* __restrict__ A, const __half* __restrict__ Bprep,
    unsigned char* __restrict__ hw1k, __half* __restrict__ hw1r, int M) {
    __shared__ char a_lds[64 * 256];   // 64 rows x 128 fp16, XOR-swizzled
    int row0 = blockIdx.x * 64;
    int tid = threadIdx.x;
    int wid = tid >> 6, lane = tid & 63;

    const float4* xf4 = reinterpret_cast<const float4*>(A);
#pragma unroll
    for (int j = 0; j < 8; ++j) {
        int g = j * 256 + tid;
        int r = g >> 5, c = g & 31;
        int gr = row0 + r;
        float4 f = (gr < M) ? xf4[(size_t)gr * 32 + c]
                            : make_float4(0.f, 0.f, 0.f, 0.f);
        int2 v;
        v.x = h2_as_int(__floats2half2_rn(f.x, f.y));
        v.y = h2_as_int(__floats2half2_rn(f.z, f.w));
        int byte = r * 256 + c * 8;
        byte ^= (r & 7) << 4;
        *reinterpret_cast<int2*>(&a_lds[byte]) = v;
    }

    v8h bf[2][4];   // [cf][ks]
#pragma unroll
    for (int cf = 0; cf < 2; ++cf)
#pragma unroll
        for (int ks = 0; ks < 4; ++ks) {
            int cb = blockIdx.y * 8 + wid * 2 + cf;
            int fi = cb * 4 + ks;
            bf[cf][ks] = *reinterpret_cast<const v8h*>(Bprep + (size_t)fi * 512 + lane * 8);
        }

    __syncthreads();

    v4f acc[4][2] = {};
#pragma unroll
    for (int ks = 0; ks < 4; ++ks) {
        v8h af[4];
#pragma unroll
        for (int rf = 0; rf < 4; ++rf) {
            int r = rf * 16 + (lane & 15);
            int byte = r * 256 + ks * 64 + (lane >> 4) * 16;
            byte ^= (r & 7) << 4;
            af[rf] = *reinterpret_cast<const v8h*>(&a_lds[byte]);
        }
#pragma unroll
        for (int rf = 0; rf < 4; ++rf)
#pragma unroll
            for (int cf = 0; cf < 2; ++cf)
                acc[rf][cf] = __builtin_amdgcn_mfma_f32_16x16x32_f16(
                    af[rf], bf[cf][ks], acc[rf][cf], 0, 0, 0);
    }

#pragma unroll
    for (int rf = 0; rf < 4; ++rf)
#pragma unroll
        for (int cf = 0; cf < 2; ++cf) {
            int gc = blockIdx.y * 128 + wid * 32 + cf * 16 + (lane & 15);
#pragma unroll
            for (int i = 0; i < 4; ++i) {
                int gr = row0 + rf * 16 + (lane >> 4) * 4 + i;
                if (gr < M) {
                    float val = acc[rf][cf][i];
                    if (gc < 192)
                        hw1k[(size_t)gr * 192 + gc] = f32_to_fp8(val);
                    else
                        hw1r[(size_t)gr * 64 + (gc - 192)] = __float2half(val);
                }
            }
        }
}

// ---------------------------------------------------------------------------
// agg1_fused v4: balanced 4-edge-chunk cooperative walk WITH explicitly
// hoisted loads (all 4 records + 12 gather words named before any consumer,
// round-12-style) -> LDS atomic accumulate -> ELU -> 64x64 matvec -> hw2h.
// ---------------------------------------------------------------------------
__global__ __launch_bounds__(256) void agg1_fused(
    const int4* __restrict__ rec, const int* __restrict__ rowptr,
    const unsigned char* __restrict__ hw1k, const __half* __restrict__ hw1r,
    const float* __restrict__ b1, const float* __restrict__ g2,
    const float* __restrict__ r2, __half* __restrict__ hw2h, int N) {
    __shared__ float Wlds[64][64];   // [k][c]: c<48 from g2, c>=48 from r2
    __shared__ float h2a[8][64];     // accumulators, then h2 values
    __shared__ int rp[9];
    int t = threadIdx.x;
    int node0 = blockIdx.x * 8;

    for (int i = t; i < 4096; i += 256) {
        int k = i >> 6, c = i & 63;
        Wlds[k][c] = (c < 48) ? g2[k * 48 + c] : r2[k * 16 + (c - 48)];
    }
    reinterpret_cast<float2*>(&h2a[0][0])[t] = make_float2(0.f, 0.f);
    int nn = min(8, N - node0);
    if (t <= nn) rp[t] = rowptr[node0 + t];
    __syncthreads();

    int beg = rp[0], end = rp[nn];
    int g = t >> 5, l = t & 31;

    // Chunked cooperative walk: group g owns edges [beg+4g, beg+4g+4) + 32k.
    // All loads hoisted into named registers BEFORE any decode/atomicAdd so
    // the compiler batches 4 rec loads + 12 gathers in flight (round-12 form).
    int j = beg + 4 * g;
    for (; j + 3 < end; j += 32) {
        int4 r0 = rec[j], r1 = rec[j + 1], r2v = rec[j + 2], r3 = rec[j + 3];
        const unsigned short* p0 = reinterpret_cast<const unsigned short*>(
            hw1k + (size_t)(r0.x & 0xFFFFFF) * 192);
        const unsigned short* p1 = reinterpret_cast<const unsigned short*>(
            hw1k + (size_t)(r1.x & 0xFFFFFF) * 192);
        const unsigned short* p2 = reinterpret_cast<const unsigned short*>(
            hw1k + (size_t)(r2v.x & 0xFFFFFF) * 192);
        const unsigned short* p3 = reinterpret_cast<const unsigned short*>(
            hw1k + (size_t)(r3.x & 0xFFFFFF) * 192);
        unsigned short w00 = p0[l], w01 = p0[32 + l], w02 = p0[64 + l];
        unsigned short w10 = p1[l], w11 = p1[32 + l], w12 = p1[64 + l];
        unsigned short w20 = p2[l], w21 = p2[32 + l], w22 = p2[64 + l];
        unsigned short w30 = p3[l], w31 = p3[32 + l], w32 = p3[64 + l];
        __half2 ha0 = int_as_h2(r0.y), hb0 = int_as_h2(r0.z);
        __half2 ha1 = int_as_h2(r1.y), hb1 = int_as_h2(r1.z);
        __half2 ha2 = int_as_h2(r2v.y), hb2 = int_as_h2(r2v.z);
        __half2 ha3 = int_as_h2(r3.y), hb3 = int_as_h2(r3.z);
        int nl0 = (r0.x >> 24) & 7, nl1 = (r1.x >> 24) & 7;
        int nl2 = (r2v.x >> 24) & 7, nl3 = (r3.x >> 24) & 7;
        {
            float g0 = __low2float(ha0), g1 = __high2float(ha0), gg2 = __low2float(hb0);
            float2 a = fp8x2_to_f32(w00), b = fp8x2_to_f32(w01), c = fp8x2_to_f32(w02);
            atomicAdd(&h2a[nl0][2 * l],     g0 * a.x + g1 * b.x + gg2 * c.x);
            atomicAdd(&h2a[nl0][2 * l + 1], g0 * a.y + g1 * b.y + gg2 * c.y);
        }
        {
            float g0 = __low2float(ha1), g1 = __high2float(ha1), gg2 = __low2float(hb1);
            float2 a = fp8x2_to_f32(w10), b = fp8x2_to_f32(w11), c = fp8x2_to_f32(w12);
            atomicAdd(&h2a[nl1][2 * l],     g0 * a.x + g1 * b.x + gg2 * c.x);
            atomicAdd(&h2a[nl1][2 * l + 1], g0 * a.y + g1 * b.y + gg2 * c.y);
        }
        {
            float g0 = __low2float(ha2), g1 = __high2float(ha2), gg2 = __low2float(hb2);
            float2 a = fp8x2_to_f32(w20), b = fp8x2_to_f32(w21), c = fp8x2_to_f32(w22);
            atomicAdd(&h2a[nl2][2 * l],     g0 * a.x + g1 * b.x + gg2 * c.x);
            atomicAdd(&h2a[nl2][2 * l + 1], g0 * a.y + g1 * b.y + gg2 * c.y);
        }
        {
            float g0 = __low2float(ha3), g1 = __high2float(ha3), gg2 = __low2float(hb3);
            float2 a = fp8x2_to_f32(w30), b = fp8x2_to_f32(w31), c = fp8x2_to_f32(w32);
            atomicAdd(&h2a[nl3][2 * l],     g0 * a.x + g1 * b.x + gg2 * c.x);
            atomicAdd(&h2a[nl3][2 * l + 1], g0 * a.y + g1 * b.y + gg2 * c.y);
        }
    }
    for (int i = 0; i < 4; ++i) {
        if (j + i < end) {
            int4 r = rec[j + i];
            int src = r.x & 0xFFFFFF;
            int nl = (r.x >> 24) & 7;
            __half2 ha = int_as_h2(r.y), hb = int_as_h2(r.z);
            float g0 = __low2float(ha), g1 = __high2float(ha), gg2 = __low2float(hb);
            const unsigned short* p = reinterpret_cast<const unsigned short*>(
                hw1k + (size_t)src * 192);
            float2 a = fp8x2_to_f32(p[l]);
            float2 b = fp8x2_to_f32(p[32 + l]);
            float2 c = fp8x2_to_f32(p[64 + l]);
            atomicAdd(&h2a[nl][2 * l],     g0 * a.x + g1 * b.x + gg2 * c.x);
            atomicAdd(&h2a[nl][2 * l + 1], g0 * a.y + g1 * b.y + gg2 * c.y);
        }
    }
    __syncthreads();

    // mean + root + bias + ELU (in place)
    {
        int nl = t >> 5;
        if (nl < nn) {
            int gn = node0 + nl;
            float d = fmaxf((float)(rp[nl + 1] - rp[nl]), 1.f);
            float2 root = __half22float2(
                reinterpret_cast<const __half2*>(hw1r + (size_t)gn * 64)[l]);
            float2 bb = reinterpret_cast<const float2*>(b1)[l];
            float v0 = h2a[nl][2 * l] / d + root.x + bb.x;
            float v1 = h2a[nl][2 * l + 1] / d + root.y + bb.y;
            h2a[nl][2 * l]     = v0 > 0.f ? v0 : expm1f(v0);
            h2a[nl][2 * l + 1] = v1 > 0.f ? v1 : expm1f(v1);
        }
    }
    __syncthreads();

    // layer-2 matvec: thread computes cols {2l, 2l+1} of its node
    {
        int nl = t >> 5;
        if (nl < nn) {
            float acc0 = 0.f, acc1 = 0.f;
#pragma unroll 8
            for (int k = 0; k < 64; ++k) {
                float hv = h2a[nl][k];
                float2 w = *reinterpret_cast<const float2*>(&Wlds[k][2 * l]);
                acc0 += hv * w.x;
                acc1 += hv * w.y;
            }
            reinterpret_cast<__half2*>(hw2h)[(size_t)(node0 + nl) * 32 + l] =
                __floats2half2_rn(acc0, acc1);
        }
    }
}

// ---------------------------------------------------------------------------
// agg2: 8 lanes per node, lane owns c = {2l, 2l+1} via half2.
// ---------------------------------------------------------------------------
__global__ __launch_bounds__(256) void agg2_kernel(
    const int4* __restrict__ rec, const int* __restrict__ rowptr,
    const __half* __restrict__ hw2h, const float* __restrict__ b2,
    float* __restrict__ out, int N) {
    int node = (blockIdx.x * 256 + threadIdx.x) >> 3;
    int l = threadIdx.x & 7;
    if (node >= N) return;
    int beg = rowptr[node], end = rowptr[node + 1];
    float ax = 0.f, ay = 0.f;
    for (int j = beg; j < end; ++j) {
        int4 r = rec[j];
        int src = r.x & 0xFFFFFF;
        __half2 hb = int_as_h2(r.z), hc = int_as_h2(r.w);
        float g0 = __high2float(hb), g1 = __low2float(hc), g2 = __high2float(hc);
        const __half2* p = reinterpret_cast<const __half2*>(hw2h + (size_t)src * 64);
        float2 f0 = __half22float2(p[l]);
        float2 f1 = __half22float2(p[8 + l]);
        float2 f2 = __half22float2(p[16 + l]);
        ax += g0 * f0.x + g1 * f1.x + g2 * f2.x;
        ay += g0 * f0.y + g1 * f1.y + g2 * f2.y;
    }
    float d = fmaxf((float)(end - beg), 1.0f);
    float2 root = __half22float2(
        reinterpret_cast<const __half2*>(hw2h + (size_t)node * 64 + 48)[l]);
    float2 bb = reinterpret_cast<const float2*>(b2)[l];
    float v0 = ax / d + root.x + bb.x;
    float v1 = ay / d + root.y + bb.y;

    float mx = fmaxf(v0, v1);
#pragma unroll
    for (int off = 4; off >= 1; off >>= 1) mx = fmaxf(mx, __shfl_xor(mx, off, 8));
    float s = __expf(v0 - mx) + __expf(v1 - mx);
#pragma unroll
    for (int off = 4; off >= 1; off >>= 1) s += __shfl_xor(s, off, 8);
    float ls = __logf(s);
    float2 o = make_float2(v0 - mx - ls, v1 - mx - ls);
    reinterpret_cast<float2*>(out + (size_t)node * 16)[l] = o;
}

// ---------------------------------------------------------------------------
extern "C" void kernel_launch(void* const* d_in, const int* in_sizes, int n_in,
                              void* d_out, int out_size, void* d_ws, size_t ws_size,
                              hipStream_t stream) {
    const float* x   = (const float*)d_in[0];
    const int*   ei  = (const int*)d_in[1];
    const float* ea  = (const float*)d_in[2];
    const float* g1  = (const float*)d_in[3];
    const float* mu1 = (const float*)d_in[4];
    const float* sg1 = (const float*)d_in[5];
    const float* r1  = (const float*)d_in[6];
    const float* b1  = (const float*)d_in[7];
    const float* g2  = (const float*)d_in[8];
    const float* mu2 = (const float*)d_in[9];
    const float* sg2 = (const float*)d_in[10];
    const float* r2  = (const float*)d_in[11];
    const float* b2  = (const float*)d_in[12];

    const int N = in_sizes[0] / 128;   // 50000
    const int E = in_sizes[2] / 2;     // 800000
    const int nbkt = (N + BKT_SIZE - 1) >> BKT_SHIFT;   // 391

    // Workspace layout
    unsigned char* hw1k = (unsigned char*)d_ws;           // N*192 fp8 (9.6MB)
    __half* hw1r = (__half*)(hw1k + (size_t)N * 192);     // N*64 fp16
    __half* hw2h = (__half*)(hw1r + (size_t)N * 64);      // N*64 fp16
    int4*   rec  = (int4*)(hw2h + (size_t)N * 64);        // E int4 (12.8MB)
    int4*   staging = rec + E;                            // E int4 (12.8MB)
    __half* Bprep = (__half*)(staging + E);               // 32768 halves
    int*    rowptr  = (int*)(Bprep + 32768);              // N+1
    int*    bcnt    = rowptr + N + 1;                     // nbkt
    int*    bbase   = bcnt + nbkt;                        // nbkt+1
    int*    bcursor = bbase + nbkt + 1;                   // nbkt
    int*    flag    = bcursor + nbkt;                     // 1

    detect_kernel<<<1, 256, 0, stream>>>(ei, flag, bcnt, nbkt);
    bhist_kernel<<<(E + 4095) / 4096, 256, 0, stream>>>(ei, flag, bcnt, E, nbkt);
    bscan_kernel<<<1, 512, 0, stream>>>(bcnt, bbase, bcursor, rowptr + N, nbkt, E);

    pass1_kernel<<<(E + 8191) / 8192, 1024, 0, stream>>>(
        ei, flag, (const float2*)ea, bcursor, staging, E, nbkt);
    pass2_kernel<<<nbkt, 256, 0, stream>>>(
        staging, bbase, mu1, sg1, mu2, sg2, rec, rowptr, N);

    // Layer 1 GEMM (MFMA): x [N,128] @ [g1|root1] -> hw1k fp8 + hw1r fp16
    bprep_kernel<<<128, 256, 0, stream>>>(g1, r1, Bprep);
    gemm1_mfma<<<dim3((N + 63) / 64, 2), 256, 0, stream>>>(x, Bprep, hw1k, hw1r, N);

    // agg1 + layer-2 GEMM fused (balanced + hoisted MLP): -> hw2h
    agg1_fused<<<(N + 7) / 8, 256, 0, stream>>>(
        rec, rowptr, hw1k, hw1r, b1, g2, r2, hw2h, N);

    agg2_kernel<<<((size_t)N * 8 + 255) / 256, 256, 0, stream>>>(
        rec, rowptr, hw2h, b2, (float*)d_out, N);
}

// Round 16
// 146.869 us; speedup vs baseline: 2.5715x; 2.5715x over previous
//
#include <hip/hip_runtime.h>
#include <hip/hip_fp16.h>

#define EPS 1e-15f
#define BKT_SHIFT 7
#define BKT_SIZE 128
#define NBKT_MAX 512

typedef _Float16 v8h __attribute__((ext_vector_type(8)));
typedef float v4f __attribute__((ext_vector_type(4)));
typedef float v2f __attribute__((ext_vector_type(2)));

#if __has_builtin(__builtin_amdgcn_cvt_pk_f32_fp8) && __has_builtin(__builtin_amdgcn_cvt_pk_fp8_f32)
#define FP8_HW 1
#else
#define FP8_HW 0
#endif

// ---------------------------------------------------------------------------
// fp8 helpers (encode in gemm1, decode in agg1 — matched paths)
// ---------------------------------------------------------------------------
__device__ __forceinline__ unsigned char f32_to_fp8(float v) {
#if FP8_HW
    int r = __builtin_amdgcn_cvt_pk_fp8_f32(v, v, 0, false);
    return (unsigned char)(r & 0xFF);
#else
    __half h = __float2half(v);
    unsigned short u; __builtin_memcpy(&u, &h, 2);
    int s = (u >> 15) << 7;
    int a = (u & 0x7FFF) + 0x40;
    if (a < (9 << 10)) return (unsigned char)s;
    int t = (a >> 7) - 64;
    if (t > 126) t = 126;
    return (unsigned char)(s | t);
#endif
}

__device__ __forceinline__ float2 fp8x2_to_f32(unsigned short w) {
#if FP8_HW
    v2f r = __builtin_amdgcn_cvt_pk_f32_fp8((int)w, false);
    return make_float2(r.x, r.y);
#else
    int b0 = w & 0xFF, b1 = w >> 8;
    unsigned short h0 = (unsigned short)((((b0 & 0x7F) + 64) << 7) | ((b0 & 0x80) << 8));
    unsigned short h1 = (unsigned short)((((b1 & 0x7F) + 64) << 7) | ((b1 & 0x80) << 8));
    __half x0, x1;
    __builtin_memcpy(&x0, &h0, 2);
    __builtin_memcpy(&x1, &h1, 2);
    return make_float2(__half2float(x0), __half2float(x1));
#endif
}

// ---------------------------------------------------------------------------
// Helpers
// ---------------------------------------------------------------------------
__device__ __forceinline__ int load_idx(const int* __restrict__ ei, int is64, int pos) {
    return is64 ? ei[(size_t)2 * pos] : ei[pos];
}

__device__ __forceinline__ int h2_as_int(__half2 h) {
    int w; __builtin_memcpy(&w, &h, 4); return w;
}
__device__ __forceinline__ __half2 int_as_h2(int w) {
    __half2 h; __builtin_memcpy(&h, &w, 4); return h;
}

// Detect int64 vs int32 edge_index; ALSO zeroes bcnt.
__global__ void detect_kernel(const int* __restrict__ ei, int* __restrict__ flag,
                              int* __restrict__ bcnt, int nbkt) {
    __shared__ int any_odd;
    if (threadIdx.x == 0) any_odd = 0;
    __syncthreads();
    for (int u = threadIdx.x; u < nbkt; u += 256) bcnt[u] = 0;
    if (ei[2 * threadIdx.x + 1] != 0) atomicOr(&any_odd, 1);
    __syncthreads();
    if (threadIdx.x == 0) *flag = any_odd ? 0 : 1;
}

// Bucket histogram: LDS-aggregated, 4096 edges/block.
__global__ __launch_bounds__(256) void bhist_kernel(
    const int* __restrict__ ei, const int* __restrict__ flag,
    int* __restrict__ bcnt, int E, int nbkt) {
    __shared__ int cnt[NBKT_MAX];
    int t = threadIdx.x;
    for (int u = t; u < nbkt; u += 256) cnt[u] = 0;
    __syncthreads();
    int is64 = *flag;
    int e0 = blockIdx.x * 4096;
#pragma unroll
    for (int i = 0; i < 16; ++i) {
        int e = e0 + i * 256 + t;
        if (e < E) atomicAdd(&cnt[load_idx(ei, is64, E + e) >> BKT_SHIFT], 1);
    }
    __syncthreads();
    for (int u = t; u < nbkt; u += 256)
        if (cnt[u]) atomicAdd(&bcnt[u], cnt[u]);
}

// Exclusive scan over bcnt[nbkt] (nbkt <= 512); also bbase[nbkt]=E, rowptr[N]=E.
__global__ void bscan_kernel(const int* __restrict__ bcnt, int* __restrict__ bbase,
                             int* __restrict__ bcursor, int* __restrict__ rowptrN,
                             int nbkt, int E) {
    __shared__ int s[512];
    int t = threadIdx.x;
    int v = (t < nbkt) ? bcnt[t] : 0;
    s[t] = v;
    __syncthreads();
    for (int o = 1; o < 512; o <<= 1) {
        int u = (t >= o) ? s[t - o] : 0;
        __syncthreads();
        s[t] += u;
        __syncthreads();
    }
    if (t < nbkt) { int ex = s[t] - v; bbase[t] = ex; bcursor[t] = ex; }
    if (t == 0) { bbase[nbkt] = E; *rowptrN = E; }
}

// ---------------------------------------------------------------------------
// Pass 1: bucket multisplit, 8192 edges per 1024-thread block, two-phase.
// ---------------------------------------------------------------------------
__global__ __launch_bounds__(1024) void pass1_kernel(
    const int* __restrict__ ei, const int* __restrict__ flag,
    const float2* __restrict__ ea, int* __restrict__ bcursor,
    int4* __restrict__ staging, int E, int nbkt) {
    __shared__ int lcnt[NBKT_MAX];
    __shared__ int lcur[NBKT_MAX];
    int t = threadIdx.x;
    if (t < nbkt) lcnt[t] = 0;
    __syncthreads();
    int is64 = *flag;
    int e0 = blockIdx.x * 8192;
    int eend = min(e0 + 8192, E);

    for (int e = e0 + t; e < eend; e += 1024)
        atomicAdd(&lcnt[load_idx(ei, is64, E + e) >> BKT_SHIFT], 1);
    __syncthreads();

    if (t < nbkt) {
        int c = lcnt[t];
        lcur[t] = c ? atomicAdd(&bcursor[t], c) : 0;
    }
    __syncthreads();

    for (int e = e0 + t; e < eend; e += 1024) {
        int src = load_idx(ei, is64, e);
        int dst = load_idx(ei, is64, E + e);
        float2 a = ea[e];
        int pos = atomicAdd(&lcur[dst >> BKT_SHIFT], 1);
        staging[pos] = make_int4(src, dst,
                                 __float_as_int(a.x), __float_as_int(a.y));
    }
}

// ---------------------------------------------------------------------------
// Pass 2: one block per bucket. Derives per-node rowptr; places records.
//   rec.x = src  (src < 2^24, upper bits zero)
// ---------------------------------------------------------------------------
__global__ __launch_bounds__(256) void pass2_kernel(
    const int4* __restrict__ staging, const int* __restrict__ bbase,
    const float* __restrict__ mu1, const float* __restrict__ sg1,
    const float* __restrict__ mu2, const float* __restrict__ sg2,
    int4* __restrict__ rec, int* __restrict__ rowptr, int N) {
    __shared__ int lcnt[BKT_SIZE];
    __shared__ int ssc[BKT_SIZE];
    __shared__ int lcur[BKT_SIZE];
    int b = blockIdx.x;
    int node0 = b << BKT_SHIFT;
    int t = threadIdx.x;
    int beg = bbase[b], end = bbase[b + 1];

    if (t < BKT_SIZE) lcnt[t] = 0;
    __syncthreads();
    for (int j = beg + t; j < end; j += 256)
        atomicAdd(&lcnt[staging[j].y & (BKT_SIZE - 1)], 1);
    __syncthreads();
    int v = (t < BKT_SIZE) ? lcnt[t] : 0;
    if (t < BKT_SIZE) ssc[t] = v;
    __syncthreads();
    for (int o = 1; o < BKT_SIZE; o <<= 1) {
        int u = (t < BKT_SIZE && t >= o) ? ssc[t - o] : 0;
        __syncthreads();
        if (t < BKT_SIZE) ssc[t] += u;
        __syncthreads();
    }
    if (t < BKT_SIZE) {
        int excl = beg + ssc[t] - v;
        lcur[t] = excl;
        if (node0 + t < N) rowptr[node0 + t] = excl;
    }
    __syncthreads();

    float m1x[3], m1y[3], i1x[3], i1y[3], m2x[3], m2y[3], i2x[3], i2y[3];
#pragma unroll
    for (int k = 0; k < 3; ++k) {
        m1x[k] = mu1[2 * k]; m1y[k] = mu1[2 * k + 1];
        float s0 = sg1[2 * k], s1 = sg1[2 * k + 1];
        i1x[k] = -0.5f / (EPS + s0 * s0); i1y[k] = -0.5f / (EPS + s1 * s1);
        m2x[k] = mu2[2 * k]; m2y[k] = mu2[2 * k + 1];
        s0 = sg2[2 * k]; s1 = sg2[2 * k + 1];
        i2x[k] = -0.5f / (EPS + s0 * s0); i2y[k] = -0.5f / (EPS + s1 * s1);
    }

    for (int j = beg + t; j < end; j += 256) {
        int4 p = staging[j];
        float ax = __int_as_float(p.z), ay = __int_as_float(p.w);
        float g1v[3], g2v[3];
#pragma unroll
        for (int k = 0; k < 3; ++k) {
            float d0 = ax - m1x[k], d1 = ay - m1y[k];
            g1v[k] = __expf(d0 * d0 * i1x[k] + d1 * d1 * i1y[k]);
            d0 = ax - m2x[k]; d1 = ay - m2y[k];
            g2v[k] = __expf(d0 * d0 * i2x[k] + d1 * d1 * i2y[k]);
        }
        int pos = atomicAdd(&lcur[p.y & (BKT_SIZE - 1)], 1);
        int4 r;
        r.x = p.x;
        r.y = h2_as_int(__floats2half2_rn(g1v[0], g1v[1]));
        r.z = h2_as_int(__floats2half2_rn(g1v[2], g2v[0]));
        r.w = h2_as_int(__floats2half2_rn(g2v[1], g2v[2]));
        rec[pos] = r;
    }
}

// ---------------------------------------------------------------------------
// Bprep: fragment-ordered fp16 copy of W = [g1 | r1]  (128 x 256).
// ---------------------------------------------------------------------------
__global__ void bprep_kernel(const float* __restrict__ g1, const float* __restrict__ r1,
                             __half* __restrict__ Bprep) {
    int gid = blockIdx.x * 256 + threadIdx.x;   // 32768 total
    if (gid >= 32768) return;
    int fi = gid >> 9;
    int lane = (gid >> 3) & 63;
    int i = gid & 7;
    int ks = fi & 3, cb = fi >> 2;
    int k = ks * 32 + (lane >> 4) * 8 + i;
    int c = cb * 16 + (lane & 15);
    float v = (c < 192) ? g1[k * 192 + c] : r1[k * 64 + (c - 192)];
    Bprep[gid] = __float2half(v);
}

// ---------------------------------------------------------------------------
// Layer-1 GEMM via MFMA f16: x [M,128] fp32 -> hw1k fp8 [M,192] + hw1r fp16 [M,64].
// ---------------------------------------------------------------------------
__global__ __launch_bounds__(256) void gemm1_mfma(
    const float* __restrict__ A, const __half* __restrict__ Bprep,
    unsigned char* __restrict__ hw1k, __half* __restrict__ hw1r, int M) {
    __shared__ char a_lds[64 * 256];   // 64 rows x 128 fp16, XOR-swizzled
    int row0 = blockIdx.x * 64;
    int tid = threadIdx.x;
    int wid = tid >> 6, lane = tid & 63;

    const float4* xf4 = reinterpret_cast<const float4*>(A);
#pragma unroll
    for (int j = 0; j < 8; ++j) {
        int g = j * 256 + tid;
        int r = g >> 5, c = g & 31;
        int gr = row0 + r;
        float4 f = (gr < M) ? xf4[(size_t)gr * 32 + c]
                            : make_float4(0.f, 0.f, 0.f, 0.f);
        int2 v;
        v.x = h2_as_int(__floats2half2_rn(f.x, f.y));
        v.y = h2_as_int(__floats2half2_rn(f.z, f.w));
        int byte = r * 256 + c * 8;
        byte ^= (r & 7) << 4;
        *reinterpret_cast<int2*>(&a_lds[byte]) = v;
    }

    v8h bf[2][4];   // [cf][ks]
#pragma unroll
    for (int cf = 0; cf < 2; ++cf)
#pragma unroll
        for (int ks = 0; ks < 4; ++ks) {
            int cb = blockIdx.y * 8 + wid * 2 + cf;
            int fi = cb * 4 + ks;
            bf[cf][ks] = *reinterpret_cast<const v8h*>(Bprep + (size_t)fi * 512 + lane * 8);
        }

    __syncthreads();

    v4f acc[4][2] = {};
#pragma unroll
    for (int ks = 0; ks < 4; ++ks) {
        v8h af[4];
#pragma unroll
        for (int rf = 0; rf < 4; ++rf) {
            int r = rf * 16 + (lane & 15);
            int byte = r * 256 + ks * 64 + (lane >> 4) * 16;
            byte ^= (r & 7) << 4;
            af[rf] = *reinterpret_cast<const v8h*>(&a_lds[byte]);
        }
#pragma unroll
        for (int rf = 0; rf < 4; ++rf)
#pragma unroll
            for (int cf = 0; cf < 2; ++cf)
                acc[rf][cf] = __builtin_amdgcn_mfma_f32_16x16x32_f16(
                    af[rf], bf[cf][ks], acc[rf][cf], 0, 0, 0);
    }

#pragma unroll
    for (int rf = 0; rf < 4; ++rf)
#pragma unroll
        for (int cf = 0; cf < 2; ++cf) {
            int gc = blockIdx.y * 128 + wid * 32 + cf * 16 + (lane & 15);
#pragma unroll
            for (int i = 0; i < 4; ++i) {
                int gr = row0 + rf * 16 + (lane >> 4) * 4 + i;
                if (gr < M) {
                    float val = acc[rf][cf][i];
                    if (gc < 192)
                        hw1k[(size_t)gr * 192 + gc] = f32_to_fp8(val);
                    else
                        hw1r[(size_t)gr * 64 + (gc - 192)] = __float2half(val);
                }
            }
        }
}

// ---------------------------------------------------------------------------
// agg1_fused v5 (round-12 structure, barrier-free epilogue): 32 lanes per
// node, REGISTER accumulation with 4-edge unrolled gather (proven MLP), then
// ELU in registers and the 64x64 layer-2 matvec via __shfl within the 32-lane
// group (no post-gather __syncthreads -> no max-of-8 imbalance).
// ---------------------------------------------------------------------------
__global__ __launch_bounds__(256) void agg1_fused(
    const int4* __restrict__ rec, const int* __restrict__ rowptr,
    const unsigned char* __restrict__ hw1k, const __half* __restrict__ hw1r,
    const float* __restrict__ b1, const float* __restrict__ g2,
    const float* __restrict__ r2, __half* __restrict__ hw2h, int N) {
    __shared__ float Wlds[64][64];   // [k][c]: c<48 from g2, c>=48 from r2
    int t = threadIdx.x;

    // Stage layer-2 weights (L2-hot, 4096 floats); only barrier in kernel.
    for (int i = t; i < 4096; i += 256) {
        int k = i >> 6, c = i & 63;
        Wlds[k][c] = (c < 48) ? g2[k * 48 + c] : r2[k * 16 + (c - 48)];
    }
    __syncthreads();

    int node = (blockIdx.x * 256 + t) >> 5;
    int l = t & 31;
    if (node >= N) return;

    int beg = rowptr[node], end = rowptr[node + 1];
    float ax0 = 0.f, ay0 = 0.f, ax1 = 0.f, ay1 = 0.f;
    int j = beg;
    for (; j + 3 < end; j += 4) {
        int4 r0 = rec[j], r1 = rec[j + 1], r2v = rec[j + 2], r3 = rec[j + 3];
        const unsigned short* p0 = reinterpret_cast<const unsigned short*>(
            hw1k + (size_t)r0.x * 192);
        const unsigned short* p1 = reinterpret_cast<const unsigned short*>(
            hw1k + (size_t)r1.x * 192);
        const unsigned short* p2 = reinterpret_cast<const unsigned short*>(
            hw1k + (size_t)r2v.x * 192);
        const unsigned short* p3 = reinterpret_cast<const unsigned short*>(
            hw1k + (size_t)r3.x * 192);
        unsigned short w00 = p0[l], w01 = p0[32 + l], w02 = p0[64 + l];
        unsigned short w10 = p1[l], w11 = p1[32 + l], w12 = p1[64 + l];
        unsigned short w20 = p2[l], w21 = p2[32 + l], w22 = p2[64 + l];
        unsigned short w30 = p3[l], w31 = p3[32 + l], w32 = p3[64 + l];
        __half2 ha0 = int_as_h2(r0.y), hb0 = int_as_h2(r0.z);
        __half2 ha1 = int_as_h2(r1.y), hb1 = int_as_h2(r1.z);
        __half2 ha2 = int_as_h2(r2v.y), hb2 = int_as_h2(r2v.z);
        __half2 ha3 = int_as_h2(r3.y), hb3 = int_as_h2(r3.z);
        {
            float g0 = __low2float(ha0), g1 = __high2float(ha0), gg2 = __low2float(hb0);
            float2 a = fp8x2_to_f32(w00), b = fp8x2_to_f32(w01), c = fp8x2_to_f32(w02);
            ax0 += g0 * a.x + g1 * b.x + gg2 * c.x;
            ay0 += g0 * a.y + g1 * b.y + gg2 * c.y;
        }
        {
            float g0 = __low2float(ha1), g1 = __high2float(ha1), gg2 = __low2float(hb1);
            float2 a = fp8x2_to_f32(w10), b = fp8x2_to_f32(w11), c = fp8x2_to_f32(w12);
            ax1 += g0 * a.x + g1 * b.x + gg2 * c.x;
            ay1 += g0 * a.y + g1 * b.y + gg2 * c.y;
        }
        {
            float g0 = __low2float(ha2), g1 = __high2float(ha2), gg2 = __low2float(hb2);
            float2 a = fp8x2_to_f32(w20), b = fp8x2_to_f32(w21), c = fp8x2_to_f32(w22);
            ax0 += g0 * a.x + g1 * b.x + gg2 * c.x;
            ay0 += g0 * a.y + g1 * b.y + gg2 * c.y;
        }
        {
            float g0 = __low2float(ha3), g1 = __high2float(ha3), gg2 = __low2float(hb3);
            float2 a = fp8x2_to_f32(w30), b = fp8x2_to_f32(w31), c = fp8x2_to_f32(w32);
            ax1 += g0 * a.x + g1 * b.x + gg2 * c.x;
            ay1 += g0 * a.y + g1 * b.y + gg2 * c.y;
        }
    }
    for (; j < end; ++j) {
        int4 r0 = rec[j];
        __half2 ha0 = int_as_h2(r0.y), hb0 = int_as_h2(r0.z);
        float g0 = __low2float(ha0), g1 = __high2float(ha0), gg2 = __low2float(hb0);
        const unsigned short* p0 = reinterpret_cast<const unsigned short*>(
            hw1k + (size_t)r0.x * 192);
        float2 a = fp8x2_to_f32(p0[l]);
        float2 b = fp8x2_to_f32(p0[32 + l]);
        float2 c = fp8x2_to_f32(p0[64 + l]);
        ax0 += g0 * a.x + g1 * b.x + gg2 * c.x;
        ay0 += g0 * a.y + g1 * b.y + gg2 * c.y;
    }

    // mean + root + bias + ELU in registers (lane l owns h2 cols 2l, 2l+1)
    float d = fmaxf((float)(end - beg), 1.0f);
    float2 root = __half22float2(
        reinterpret_cast<const __half2*>(hw1r + (size_t)node * 64)[l]);
    float2 bb = reinterpret_cast<const float2*>(b1)[l];
    float v0 = (ax0 + ax1) / d + root.x + bb.x;
    float v1 = (ay0 + ay1) / d + root.y + bb.y;
    float e0 = v0 > 0.f ? v0 : expm1f(v0);
    float e1 = v1 > 0.f ? v1 : expm1f(v1);

    // layer-2 matvec via shfl within the 32-lane group: cols {2l, 2l+1}
    float acc0 = 0.f, acc1 = 0.f;
#pragma unroll 8
    for (int m = 0; m < 32; ++m) {
        float h0 = __shfl(e0, m, 32);   // h2[2m]
        float h1 = __shfl(e1, m, 32);   // h2[2m+1]
        float2 wa = *reinterpret_cast<const float2*>(&Wlds[2 * m][2 * l]);
        float2 wb = *reinterpret_cast<const float2*>(&Wlds[2 * m + 1][2 * l]);
        acc0 += h0 * wa.x + h1 * wb.x;
        acc1 += h0 * wa.y + h1 * wb.y;
    }
    reinterpret_cast<__half2*>(hw2h)[(size_t)node * 32 + l] =
        __floats2half2_rn(acc0, acc1);
}

// ---------------------------------------------------------------------------
// agg2: 8 lanes per node, lane owns c = {2l, 2l+1} via half2.
// ---------------------------------------------------------------------------
__global__ __launch_bounds__(256) void agg2_kernel(
    const int4* __restrict__ rec, const int* __restrict__ rowptr,
    const __half* __restrict__ hw2h, const float* __restrict__ b2,
    float* __restrict__ out, int N) {
    int node = (blockIdx.x * 256 + threadIdx.x) >> 3;
    int l = threadIdx.x & 7;
    if (node >= N) return;
    int beg = rowptr[node], end = rowptr[node + 1];
    float ax = 0.f, ay = 0.f;
    for (int j = beg; j < end; ++j) {
        int4 r = rec[j];
        __half2 hb = int_as_h2(r.z), hc = int_as_h2(r.w);
        float g0 = __high2float(hb), g1 = __low2float(hc), g2 = __high2float(hc);
        const __half2* p = reinterpret_cast<const __half2*>(hw2h + (size_t)r.x * 64);
        float2 f0 = __half22float2(p[l]);
        float2 f1 = __half22float2(p[8 + l]);
        float2 f2 = __half22float2(p[16 + l]);
        ax += g0 * f0.x + g1 * f1.x + g2 * f2.x;
        ay += g0 * f0.y + g1 * f1.y + g2 * f2.y;
    }
    float d = fmaxf((float)(end - beg), 1.0f);
    float2 root = __half22float2(
        reinterpret_cast<const __half2*>(hw2h + (size_t)node * 64 + 48)[l]);
    float2 bb = reinterpret_cast<const float2*>(b2)[l];
    float v0 = ax / d + root.x + bb.x;
    float v1 = ay / d + root.y + bb.y;

    float mx = fmaxf(v0, v1);
#pragma unroll
    for (int off = 4; off >= 1; off >>= 1) mx = fmaxf(mx, __shfl_xor(mx, off, 8));
    float s = __expf(v0 - mx) + __expf(v1 - mx);
#pragma unroll
    for (int off = 4; off >= 1; off >>= 1) s += __shfl_xor(s, off, 8);
    float ls = __logf(s);
    float2 o = make_float2(v0 - mx - ls, v1 - mx - ls);
    reinterpret_cast<float2*>(out + (size_t)node * 16)[l] = o;
}

// ---------------------------------------------------------------------------
extern "C" void kernel_launch(void* const* d_in, const int* in_sizes, int n_in,
                              void* d_out, int out_size, void* d_ws, size_t ws_size,
                              hipStream_t stream) {
    const float* x   = (const float*)d_in[0];
    const int*   ei  = (const int*)d_in[1];
    const float* ea  = (const float*)d_in[2];
    const float* g1  = (const float*)d_in[3];
    const float* mu1 = (const float*)d_in[4];
    const float* sg1 = (const float*)d_in[5];
    const float* r1  = (const float*)d_in[6];
    const float* b1  = (const float*)d_in[7];
    const float* g2  = (const float*)d_in[8];
    const float* mu2 = (const float*)d_in[9];
    const float* sg2 = (const float*)d_in[10];
    const float* r2  = (const float*)d_in[11];
    const float* b2  = (const float*)d_in[12];

    const int N = in_sizes[0] / 128;   // 50000
    const int E = in_sizes[2] / 2;     // 800000
    const int nbkt = (N + BKT_SIZE - 1) >> BKT_SHIFT;   // 391

    // Workspace layout
    unsigned char* hw1k = (unsigned char*)d_ws;           // N*192 fp8 (9.6MB)
    __half* hw1r = (__half*)(hw1k + (size_t)N * 192);     // N*64 fp16
    __half* hw2h = (__half*)(hw1r + (size_t)N * 64);      // N*64 fp16
    int4*   rec  = (int4*)(hw2h + (size_t)N * 64);        // E int4 (12.8MB)
    int4*   staging = rec + E;                            // E int4 (12.8MB)
    __half* Bprep = (__half*)(staging + E);               // 32768 halves
    int*    rowptr  = (int*)(Bprep + 32768);              // N+1
    int*    bcnt    = rowptr + N + 1;                     // nbkt
    int*    bbase   = bcnt + nbkt;                        // nbkt+1
    int*    bcursor = bbase + nbkt + 1;                   // nbkt
    int*    flag    = bcursor + nbkt;                     // 1

    detect_kernel<<<1, 256, 0, stream>>>(ei, flag, bcnt, nbkt);
    bhist_kernel<<<(E + 4095) / 4096, 256, 0, stream>>>(ei, flag, bcnt, E, nbkt);
    bscan_kernel<<<1, 512, 0, stream>>>(bcnt, bbase, bcursor, rowptr + N, nbkt, E);

    pass1_kernel<<<(E + 8191) / 8192, 1024, 0, stream>>>(
        ei, flag, (const float2*)ea, bcursor, staging, E, nbkt);
    pass2_kernel<<<nbkt, 256, 0, stream>>>(
        staging, bbase, mu1, sg1, mu2, sg2, rec, rowptr, N);

    // Layer 1 GEMM (MFMA): x [N,128] @ [g1|root1] -> hw1k fp8 + hw1r fp16
    bprep_kernel<<<128, 256, 0, stream>>>(g1, r1, Bprep);
    gemm1_mfma<<<dim3((N + 63) / 64, 2), 256, 0, stream>>>(x, Bprep, hw1k, hw1r, N);

    // agg1 + layer-2 GEMM fused (register acc + shfl matvec): -> hw2h
    agg1_fused<<<((size_t)N * 32 + 255) / 256, 256, 0, stream>>>(
        rec, rowptr, hw1k, hw1r, b1, g2, r2, hw2h, N);

    agg2_kernel<<<((size_t)N * 8 + 255) / 256, 256, 0, stream>>>(
        rec, rowptr, hw2h, b2, (float*)d_out, N);
}

// Round 17
// 129.218 us; speedup vs baseline: 2.9228x; 1.1366x over previous
//
#include <hip/hip_runtime.h>
#include <hip/hip_fp16.h>

#define EPS 1e-15f
#define BKT_SHIFT 7
#define BKT_SIZE 128
#define NBKT_MAX 512

typedef _Float16 v8h __attribute__((ext_vector_type(8)));
typedef float v4f __attribute__((ext_vector_type(4)));
typedef float v2f __attribute__((ext_vector_type(2)));

#if __has_builtin(__builtin_amdgcn_cvt_pk_f32_fp8) && __has_builtin(__builtin_amdgcn_cvt_pk_fp8_f32)
#define FP8_HW 1
#else
#define FP8_HW 0
#endif

// ---------------------------------------------------------------------------
// fp8 helpers (encode in gemm1/agg1-epilogue, decode in agg1/agg2 — matched)
// ---------------------------------------------------------------------------
__device__ __forceinline__ unsigned char f32_to_fp8(float v) {
#if FP8_HW
    int r = __builtin_amdgcn_cvt_pk_fp8_f32(v, v, 0, false);
    return (unsigned char)(r & 0xFF);
#else
    __half h = __float2half(v);
    unsigned short u; __builtin_memcpy(&u, &h, 2);
    int s = (u >> 15) << 7;
    int a = (u & 0x7FFF) + 0x40;
    if (a < (9 << 10)) return (unsigned char)s;
    int t = (a >> 7) - 64;
    if (t > 126) t = 126;
    return (unsigned char)(s | t);
#endif
}

__device__ __forceinline__ unsigned short f32x2_to_fp8x2(float v0, float v1) {
#if FP8_HW
    int r = __builtin_amdgcn_cvt_pk_fp8_f32(v0, v1, 0, false);
    return (unsigned short)(r & 0xFFFF);
#else
    return (unsigned short)(f32_to_fp8(v0) | (f32_to_fp8(v1) << 8));
#endif
}

__device__ __forceinline__ float2 fp8x2_to_f32(unsigned short w) {
#if FP8_HW
    v2f r = __builtin_amdgcn_cvt_pk_f32_fp8((int)w, false);
    return make_float2(r.x, r.y);
#else
    int b0 = w & 0xFF, b1 = w >> 8;
    unsigned short h0 = (unsigned short)((((b0 & 0x7F) + 64) << 7) | ((b0 & 0x80) << 8));
    unsigned short h1 = (unsigned short)((((b1 & 0x7F) + 64) << 7) | ((b1 & 0x80) << 8));
    __half x0, x1;
    __builtin_memcpy(&x0, &h0, 2);
    __builtin_memcpy(&x1, &h1, 2);
    return make_float2(__half2float(x0), __half2float(x1));
#endif
}

// ---------------------------------------------------------------------------
// Helpers
// ---------------------------------------------------------------------------
__device__ __forceinline__ int load_idx(const int* __restrict__ ei, int is64, int pos) {
    return is64 ? ei[(size_t)2 * pos] : ei[pos];
}

__device__ __forceinline__ int h2_as_int(__half2 h) {
    int w; __builtin_memcpy(&w, &h, 4); return w;
}
__device__ __forceinline__ __half2 int_as_h2(int w) {
    __half2 h; __builtin_memcpy(&h, &w, 4); return h;
}

// Detect int64 vs int32 edge_index; ALSO zeroes bcnt.
__global__ void detect_kernel(const int* __restrict__ ei, int* __restrict__ flag,
                              int* __restrict__ bcnt, int nbkt) {
    __shared__ int any_odd;
    if (threadIdx.x == 0) any_odd = 0;
    __syncthreads();
    for (int u = threadIdx.x; u < nbkt; u += 256) bcnt[u] = 0;
    if (ei[2 * threadIdx.x + 1] != 0) atomicOr(&any_odd, 1);
    __syncthreads();
    if (threadIdx.x == 0) *flag = any_odd ? 0 : 1;
}

// Bucket histogram: LDS-aggregated, 4096 edges/block.
__global__ __launch_bounds__(256) void bhist_kernel(
    const int* __restrict__ ei, const int* __restrict__ flag,
    int* __restrict__ bcnt, int E, int nbkt) {
    __shared__ int cnt[NBKT_MAX];
    int t = threadIdx.x;
    for (int u = t; u < nbkt; u += 256) cnt[u] = 0;
    __syncthreads();
    int is64 = *flag;
    int e0 = blockIdx.x * 4096;
#pragma unroll
    for (int i = 0; i < 16; ++i) {
        int e = e0 + i * 256 + t;
        if (e < E) atomicAdd(&cnt[load_idx(ei, is64, E + e) >> BKT_SHIFT], 1);
    }
    __syncthreads();
    for (int u = t; u < nbkt; u += 256)
        if (cnt[u]) atomicAdd(&bcnt[u], cnt[u]);
}

// Exclusive scan over bcnt[nbkt] (nbkt <= 512); also bbase[nbkt]=E, rowptr[N]=E.
__global__ void bscan_kernel(const int* __restrict__ bcnt, int* __restrict__ bbase,
                             int* __restrict__ bcursor, int* __restrict__ rowptrN,
                             int nbkt, int E) {
    __shared__ int s[512];
    int t = threadIdx.x;
    int v = (t < nbkt) ? bcnt[t] : 0;
    s[t] = v;
    __syncthreads();
    for (int o = 1; o < 512; o <<= 1) {
        int u = (t >= o) ? s[t - o] : 0;
        __syncthreads();
        s[t] += u;
        __syncthreads();
    }
    if (t < nbkt) { int ex = s[t] - v; bbase[t] = ex; bcursor[t] = ex; }
    if (t == 0) { bbase[nbkt] = E; *rowptrN = E; }
}

// ---------------------------------------------------------------------------
// Pass 1: bucket multisplit, 8192 edges per 1024-thread block, two-phase.
// ---------------------------------------------------------------------------
__global__ __launch_bounds__(1024) void pass1_kernel(
    const int* __restrict__ ei, const int* __restrict__ flag,
    const float2* __restrict__ ea, int* __restrict__ bcursor,
    int4* __restrict__ staging, int E, int nbkt) {
    __shared__ int lcnt[NBKT_MAX];
    __shared__ int lcur[NBKT_MAX];
    int t = threadIdx.x;
    if (t < nbkt) lcnt[t] = 0;
    __syncthreads();
    int is64 = *flag;
    int e0 = blockIdx.x * 8192;
    int eend = min(e0 + 8192, E);

    for (int e = e0 + t; e < eend; e += 1024)
        atomicAdd(&lcnt[load_idx(ei, is64, E + e) >> BKT_SHIFT], 1);
    __syncthreads();

    if (t < nbkt) {
        int c = lcnt[t];
        lcur[t] = c ? atomicAdd(&bcursor[t], c) : 0;
    }
    __syncthreads();

    for (int e = e0 + t; e < eend; e += 1024) {
        int src = load_idx(ei, is64, e);
        int dst = load_idx(ei, is64, E + e);
        float2 a = ea[e];
        int pos = atomicAdd(&lcur[dst >> BKT_SHIFT], 1);
        staging[pos] = make_int4(src, dst,
                                 __float_as_int(a.x), __float_as_int(a.y));
    }
}

// ---------------------------------------------------------------------------
// Pass 2: one block per bucket. Derives per-node rowptr; places records.
//   rec.x = src (plain)
// ---------------------------------------------------------------------------
__global__ __launch_bounds__(256) void pass2_kernel(
    const int4* __restrict__ staging, const int* __restrict__ bbase,
    const float* __restrict__ mu1, const float* __restrict__ sg1,
    const float* __restrict__ mu2, const float* __restrict__ sg2,
    int4* __restrict__ rec, int* __restrict__ rowptr, int N) {
    __shared__ int lcnt[BKT_SIZE];
    __shared__ int ssc[BKT_SIZE];
    __shared__ int lcur[BKT_SIZE];
    int b = blockIdx.x;
    int node0 = b << BKT_SHIFT;
    int t = threadIdx.x;
    int beg = bbase[b], end = bbase[b + 1];

    if (t < BKT_SIZE) lcnt[t] = 0;
    __syncthreads();
    for (int j = beg + t; j < end; j += 256)
        atomicAdd(&lcnt[staging[j].y & (BKT_SIZE - 1)], 1);
    __syncthreads();
    int v = (t < BKT_SIZE) ? lcnt[t] : 0;
    if (t < BKT_SIZE) ssc[t] = v;
    __syncthreads();
    for (int o = 1; o < BKT_SIZE; o <<= 1) {
        int u = (t < BKT_SIZE && t >= o) ? ssc[t - o] : 0;
        __syncthreads();
        if (t < BKT_SIZE) ssc[t] += u;
        __syncthreads();
    }
    if (t < BKT_SIZE) {
        int excl = beg + ssc[t] - v;
        lcur[t] = excl;
        if (node0 + t < N) rowptr[node0 + t] = excl;
    }
    __syncthreads();

    float m1x[3], m1y[3], i1x[3], i1y[3], m2x[3], m2y[3], i2x[3], i2y[3];
#pragma unroll
    for (int k = 0; k < 3; ++k) {
        m1x[k] = mu1[2 * k]; m1y[k] = mu1[2 * k + 1];
        float s0 = sg1[2 * k], s1 = sg1[2 * k + 1];
        i1x[k] = -0.5f / (EPS + s0 * s0); i1y[k] = -0.5f / (EPS + s1 * s1);
        m2x[k] = mu2[2 * k]; m2y[k] = mu2[2 * k + 1];
        s0 = sg2[2 * k]; s1 = sg2[2 * k + 1];
        i2x[k] = -0.5f / (EPS + s0 * s0); i2y[k] = -0.5f / (EPS + s1 * s1);
    }

    for (int j = beg + t; j < end; j += 256) {
        int4 p = staging[j];
        float ax = __int_as_float(p.z), ay = __int_as_float(p.w);
        float g1v[3], g2v[3];
#pragma unroll
        for (int k = 0; k < 3; ++k) {
            float d0 = ax - m1x[k], d1 = ay - m1y[k];
            g1v[k] = __expf(d0 * d0 * i1x[k] + d1 * d1 * i1y[k]);
            d0 = ax - m2x[k]; d1 = ay - m2y[k];
            g2v[k] = __expf(d0 * d0 * i2x[k] + d1 * d1 * i2y[k]);
        }
        int pos = atomicAdd(&lcur[p.y & (BKT_SIZE - 1)], 1);
        int4 r;
        r.x = p.x;
        r.y = h2_as_int(__floats2half2_rn(g1v[0], g1v[1]));
        r.z = h2_as_int(__floats2half2_rn(g1v[2], g2v[0]));
        r.w = h2_as_int(__floats2half2_rn(g2v[1], g2v[2]));
        rec[pos] = r;
    }
}

// ---------------------------------------------------------------------------
// Bprep: fragment-ordered fp16 copy of W = [g1 | r1]  (128 x 256).
// ---------------------------------------------------------------------------
__global__ void bprep_kernel(const float* __restrict__ g1, const float* __restrict__ r1,
                             __half* __restrict__ Bprep) {
    int gid = blockIdx.x * 256 + threadIdx.x;   // 32768 total
    if (gid >= 32768) return;
    int fi = gid >> 9;
    int lane = (gid >> 3) & 63;
    int i = gid & 7;
    int ks = fi & 3, cb = fi >> 2;
    int k = ks * 32 + (lane >> 4) * 8 + i;
    int c = cb * 16 + (lane & 15);
    float v = (c < 192) ? g1[k * 192 + c] : r1[k * 64 + (c - 192)];
    Bprep[gid] = __float2half(v);
}

// ---------------------------------------------------------------------------
// Layer-1 GEMM via MFMA f16: x [M,128] fp32 -> hw1k fp8 [M,192] + hw1r fp16 [M,64].
// ---------------------------------------------------------------------------
__global__ __launch_bounds__(256) void gemm1_mfma(
    const float* __restrict__ A, const __half* __restrict__ Bprep,
    unsigned char* __restrict__ hw1k, __half* __restrict__ hw1r, int M) {
    __shared__ char a_lds[64 * 256];   // 64 rows x 128 fp16, XOR-swizzled
    int row0 = blockIdx.x * 64;
    int tid = threadIdx.x;
    int wid = tid >> 6, lane = tid & 63;

    const float4* xf4 = reinterpret_cast<const float4*>(A);
#pragma unroll
    for (int j = 0; j < 8; ++j) {
        int g = j * 256 + tid;
        int r = g >> 5, c = g & 31;
        int gr = row0 + r;
        float4 f = (gr < M) ? xf4[(size_t)gr * 32 + c]
                            : make_float4(0.f, 0.f, 0.f, 0.f);
        int2 v;
        v.x = h2_as_int(__floats2half2_rn(f.x, f.y));
        v.y = h2_as_int(__floats2half2_rn(f.z, f.w));
        int byte = r * 256 + c * 8;
        byte ^= (r & 7) << 4;
        *reinterpret_cast<int2*>(&a_lds[byte]) = v;
    }

    v8h bf[2][4];   // [cf][ks]
#pragma unroll
    for (int cf = 0; cf < 2; ++cf)
#pragma unroll
        for (int ks = 0; ks < 4; ++ks) {
            int cb = blockIdx.y * 8 + wid * 2 + cf;
            int fi = cb * 4 + ks;
            bf[cf][ks] = *reinterpret_cast<const v8h*>(Bprep + (size_t)fi * 512 + lane * 8);
        }

    __syncthreads();

    v4f acc[4][2] = {};
#pragma unroll
    for (int ks = 0; ks < 4; ++ks) {
        v8h af[4];
#pragma unroll
        for (int rf = 0; rf < 4; ++rf) {
            int r = rf * 16 + (lane & 15);
            int byte = r * 256 + ks * 64 + (lane >> 4) * 16;
            byte ^= (r & 7) << 4;
            af[rf] = *reinterpret_cast<const v8h*>(&a_lds[byte]);
        }
#pragma unroll
        for (int rf = 0; rf < 4; ++rf)
#pragma unroll
            for (int cf = 0; cf < 2; ++cf)
                acc[rf][cf] = __builtin_amdgcn_mfma_f32_16x16x32_f16(
                    af[rf], bf[cf][ks], acc[rf][cf], 0, 0, 0);
    }

#pragma unroll
    for (int rf = 0; rf < 4; ++rf)
#pragma unroll
        for (int cf = 0; cf < 2; ++cf) {
            int gc = blockIdx.y * 128 + wid * 32 + cf * 16 + (lane & 15);
#pragma unroll
            for (int i = 0; i < 4; ++i) {
                int gr = row0 + rf * 16 + (lane >> 4) * 4 + i;
                if (gr < M) {
                    float val = acc[rf][cf][i];
                    if (gc < 192)
                        hw1k[(size_t)gr * 192 + gc] = f32_to_fp8(val);
                    else
                        hw1r[(size_t)gr * 64 + (gc - 192)] = __float2half(val);
                }
            }
        }
}

// ---------------------------------------------------------------------------
// agg1_fused (round-12 barrier epilogue): 32 lanes per node, 8 nodes per
// 256-thr block. Register-accumulated fp8 gather (4-edge unrolled, proven
// MLP) -> ELU h2 row in LDS -> barrier -> 64x64 matvec with LDS [g2|r2]
// -> hw2k fp8 (cols 0..47) + hw2r fp16 (cols 48..63).
// ---------------------------------------------------------------------------
__global__ __launch_bounds__(256) void agg1_fused(
    const int4* __restrict__ rec, const int* __restrict__ rowptr,
    const unsigned char* __restrict__ hw1k, const __half* __restrict__ hw1r,
    const float* __restrict__ b1, const float* __restrict__ g2,
    const float* __restrict__ r2, unsigned char* __restrict__ hw2k,
    __half* __restrict__ hw2r, int N) {
    __shared__ float Wlds[64][64];   // [k][c]: c<48 from g2, c>=48 from r2
    __shared__ float h2s[8][64];
    int t = threadIdx.x;

    for (int i = t; i < 4096; i += 256) {
        int k = i >> 6, c = i & 63;
        Wlds[k][c] = (c < 48) ? g2[k * 48 + c] : r2[k * 16 + (c - 48)];
    }

    int node = (blockIdx.x * 256 + t) >> 5;
    int nl = (t >> 5) & 7;
    int l = t & 31;
    bool active = node < N;

    float ax0 = 0.f, ay0 = 0.f, ax1 = 0.f, ay1 = 0.f;
    int beg = 0, end = 0;
    if (active) { beg = rowptr[node]; end = rowptr[node + 1]; }
    int j = beg;
    for (; j + 3 < end; j += 4) {
        int4 r0 = rec[j], r1 = rec[j + 1], r2v = rec[j + 2], r3 = rec[j + 3];
        const unsigned short* p0 = reinterpret_cast<const unsigned short*>(
            hw1k + (size_t)r0.x * 192);
        const unsigned short* p1 = reinterpret_cast<const unsigned short*>(
            hw1k + (size_t)r1.x * 192);
        const unsigned short* p2 = reinterpret_cast<const unsigned short*>(
            hw1k + (size_t)r2v.x * 192);
        const unsigned short* p3 = reinterpret_cast<const unsigned short*>(
            hw1k + (size_t)r3.x * 192);
        unsigned short w00 = p0[l], w01 = p0[32 + l], w02 = p0[64 + l];
        unsigned short w10 = p1[l], w11 = p1[32 + l], w12 = p1[64 + l];
        unsigned short w20 = p2[l], w21 = p2[32 + l], w22 = p2[64 + l];
        unsigned short w30 = p3[l], w31 = p3[32 + l], w32 = p3[64 + l];
        __half2 ha0 = int_as_h2(r0.y), hb0 = int_as_h2(r0.z);
        __half2 ha1 = int_as_h2(r1.y), hb1 = int_as_h2(r1.z);
        __half2 ha2 = int_as_h2(r2v.y), hb2 = int_as_h2(r2v.z);
        __half2 ha3 = int_as_h2(r3.y), hb3 = int_as_h2(r3.z);
        {
            float g0 = __low2float(ha0), g1 = __high2float(ha0), gg2 = __low2float(hb0);
            float2 a = fp8x2_to_f32(w00), b = fp8x2_to_f32(w01), c = fp8x2_to_f32(w02);
            ax0 += g0 * a.x + g1 * b.x + gg2 * c.x;
            ay0 += g0 * a.y + g1 * b.y + gg2 * c.y;
        }
        {
            float g0 = __low2float(ha1), g1 = __high2float(ha1), gg2 = __low2float(hb1);
            float2 a = fp8x2_to_f32(w10), b = fp8x2_to_f32(w11), c = fp8x2_to_f32(w12);
            ax1 += g0 * a.x + g1 * b.x + gg2 * c.x;
            ay1 += g0 * a.y + g1 * b.y + gg2 * c.y;
        }
        {
            float g0 = __low2float(ha2), g1 = __high2float(ha2), gg2 = __low2float(hb2);
            float2 a = fp8x2_to_f32(w20), b = fp8x2_to_f32(w21), c = fp8x2_to_f32(w22);
            ax0 += g0 * a.x + g1 * b.x + gg2 * c.x;
            ay0 += g0 * a.y + g1 * b.y + gg2 * c.y;
        }
        {
            float g0 = __low2float(ha3), g1 = __high2float(ha3), gg2 = __low2float(hb3);
            float2 a = fp8x2_to_f32(w30), b = fp8x2_to_f32(w31), c = fp8x2_to_f32(w32);
            ax1 += g0 * a.x + g1 * b.x + gg2 * c.x;
            ay1 += g0 * a.y + g1 * b.y + gg2 * c.y;
        }
    }
    for (; j < end; ++j) {
        int4 r0 = rec[j];
        __half2 ha0 = int_as_h2(r0.y), hb0 = int_as_h2(r0.z);
        float g0 = __low2float(ha0), g1 = __high2float(ha0), gg2 = __low2float(hb0);
        const unsigned short* p0 = reinterpret_cast<const unsigned short*>(
            hw1k + (size_t)r0.x * 192);
        float2 a = fp8x2_to_f32(p0[l]);
        float2 b = fp8x2_to_f32(p0[32 + l]);
        float2 c = fp8x2_to_f32(p0[64 + l]);
        ax0 += g0 * a.x + g1 * b.x + gg2 * c.x;
        ay0 += g0 * a.y + g1 * b.y + gg2 * c.y;
    }
    if (active) {
        float d = fmaxf((float)(end - beg), 1.0f);
        float2 root = __half22float2(
            reinterpret_cast<const __half2*>(hw1r + (size_t)node * 64)[l]);
        float2 bb = reinterpret_cast<const float2*>(b1)[l];
        float v0 = (ax0 + ax1) / d + root.x + bb.x;
        float v1 = (ay0 + ay1) / d + root.y + bb.y;
        h2s[nl][2 * l]     = v0 > 0.f ? v0 : expm1f(v0);
        h2s[nl][2 * l + 1] = v1 > 0.f ? v1 : expm1f(v1);
    }
    __syncthreads();

    // Layer-2 matvec: thread computes cols {2l, 2l+1} of its node slot.
    if (active) {
        float acc0 = 0.f, acc1 = 0.f;
#pragma unroll 8
        for (int k = 0; k < 64; ++k) {
            float hv = h2s[nl][k];                       // LDS broadcast
            float2 w = *reinterpret_cast<const float2*>(&Wlds[k][2 * l]);
            acc0 += hv * w.x;
            acc1 += hv * w.y;
        }
        int c0 = 2 * l;
        if (c0 < 48) {
            *reinterpret_cast<unsigned short*>(hw2k + (size_t)node * 48 + c0) =
                f32x2_to_fp8x2(acc0, acc1);
        } else {
            reinterpret_cast<__half2*>(hw2r + (size_t)node * 16)[l - 24] =
                __floats2half2_rn(acc0, acc1);
        }
    }
}

// ---------------------------------------------------------------------------
// agg2: 8 lanes per node, lane owns c = {2l, 2l+1}; fp8 gather table (48B row
// = ~1 cache line per edge) + fp16 root. Fused mean+root+bias+log_softmax.
// ---------------------------------------------------------------------------
__global__ __launch_bounds__(256) void agg2_kernel(
    const int4* __restrict__ rec, const int* __restrict__ rowptr,
    const unsigned char* __restrict__ hw2k, const __half* __restrict__ hw2r,
    const float* __restrict__ b2, float* __restrict__ out, int N) {
    int node = (blockIdx.x * 256 + threadIdx.x) >> 3;
    int l = threadIdx.x & 7;
    if (node >= N) return;
    int beg = rowptr[node], end = rowptr[node + 1];
    float ax = 0.f, ay = 0.f;
    for (int j = beg; j < end; ++j) {
        int4 r = rec[j];
        __half2 hb = int_as_h2(r.z), hc = int_as_h2(r.w);
        float g0 = __high2float(hb), g1 = __low2float(hc), g2 = __high2float(hc);
        const unsigned short* p = reinterpret_cast<const unsigned short*>(
            hw2k + (size_t)r.x * 48);
        float2 f0 = fp8x2_to_f32(p[l]);
        float2 f1 = fp8x2_to_f32(p[8 + l]);
        float2 f2 = fp8x2_to_f32(p[16 + l]);
        ax += g0 * f0.x + g1 * f1.x + g2 * f2.x;
        ay += g0 * f0.y + g1 * f1.y + g2 * f2.y;
    }
    float d = fmaxf((float)(end - beg), 1.0f);
    float2 root = __half22float2(
        reinterpret_cast<const __half2*>(hw2r + (size_t)node * 16)[l]);
    float2 bb = reinterpret_cast<const float2*>(b2)[l];
    float v0 = ax / d + root.x + bb.x;
    float v1 = ay / d + root.y + bb.y;

    float mx = fmaxf(v0, v1);
#pragma unroll
    for (int off = 4; off >= 1; off >>= 1) mx = fmaxf(mx, __shfl_xor(mx, off, 8));
    float s = __expf(v0 - mx) + __expf(v1 - mx);
#pragma unroll
    for (int off = 4; off >= 1; off >>= 1) s += __shfl_xor(s, off, 8);
    float ls = __logf(s);
    float2 o = make_float2(v0 - mx - ls, v1 - mx - ls);
    reinterpret_cast<float2*>(out + (size_t)node * 16)[l] = o;
}

// ---------------------------------------------------------------------------
extern "C" void kernel_launch(void* const* d_in, const int* in_sizes, int n_in,
                              void* d_out, int out_size, void* d_ws, size_t ws_size,
                              hipStream_t stream) {
    const float* x   = (const float*)d_in[0];
    const int*   ei  = (const int*)d_in[1];
    const float* ea  = (const float*)d_in[2];
    const float* g1  = (const float*)d_in[3];
    const float* mu1 = (const float*)d_in[4];
    const float* sg1 = (const float*)d_in[5];
    const float* r1  = (const float*)d_in[6];
    const float* b1  = (const float*)d_in[7];
    const float* g2  = (const float*)d_in[8];
    const float* mu2 = (const float*)d_in[9];
    const float* sg2 = (const float*)d_in[10];
    const float* r2  = (const float*)d_in[11];
    const float* b2  = (const float*)d_in[12];

    const int N = in_sizes[0] / 128;   // 50000
    const int E = in_sizes[2] / 2;     // 800000
    const int nbkt = (N + BKT_SIZE - 1) >> BKT_SHIFT;   // 391

    // Workspace layout
    unsigned char* hw1k = (unsigned char*)d_ws;           // N*192 fp8 (9.6MB)
    __half* hw1r = (__half*)(hw1k + (size_t)N * 192);     // N*64 fp16
    unsigned char* hw2k = (unsigned char*)(hw1r + (size_t)N * 64);  // N*48 fp8
    __half* hw2r = (__half*)(hw2k + (size_t)N * 48);      // N*16 fp16
    int4*   rec  = (int4*)((char*)hw2r + (size_t)N * 32); // E int4 (12.8MB)
    int4*   staging = rec + E;                            // E int4 (12.8MB)
    __half* Bprep = (__half*)(staging + E);               // 32768 halves
    int*    rowptr  = (int*)(Bprep + 32768);              // N+1
    int*    bcnt    = rowptr + N + 1;                     // nbkt
    int*    bbase   = bcnt + nbkt;                        // nbkt+1
    int*    bcursor = bbase + nbkt + 1;                   // nbkt
    int*    flag    = bcursor + nbkt;                     // 1

    detect_kernel<<<1, 256, 0, stream>>>(ei, flag, bcnt, nbkt);
    bhist_kernel<<<(E + 4095) / 4096, 256, 0, stream>>>(ei, flag, bcnt, E, nbkt);
    bscan_kernel<<<1, 512, 0, stream>>>(bcnt, bbase, bcursor, rowptr + N, nbkt, E);

    pass1_kernel<<<(E + 8191) / 8192, 1024, 0, stream>>>(
        ei, flag, (const float2*)ea, bcursor, staging, E, nbkt);
    pass2_kernel<<<nbkt, 256, 0, stream>>>(
        staging, bbase, mu1, sg1, mu2, sg2, rec, rowptr, N);

    // Layer 1 GEMM (MFMA): x [N,128] @ [g1|root1] -> hw1k fp8 + hw1r fp16
    bprep_kernel<<<128, 256, 0, stream>>>(g1, r1, Bprep);
    gemm1_mfma<<<dim3((N + 63) / 64, 2), 256, 0, stream>>>(x, Bprep, hw1k, hw1r, N);

    // agg1 + layer-2 GEMM fused (barrier matvec): -> hw2k fp8 + hw2r fp16
    agg1_fused<<<((size_t)N * 32 + 255) / 256, 256, 0, stream>>>(
        rec, rowptr, hw1k, hw1r, b1, g2, r2, hw2k, hw2r, N);

    agg2_kernel<<<((size_t)N * 8 + 255) / 256, 256, 0, stream>>>(
        rec, rowptr, hw2k, hw2r, b2, (float*)d_out, N);
}

// Round 18
// 128.439 us; speedup vs baseline: 2.9405x; 1.0061x over previous
//
#include <hip/hip_runtime.h>
#include <hip/hip_fp16.h>

#define EPS 1e-15f
#define BKT_SHIFT 7
#define BKT_SIZE 128
#define NBKT_MAX 512

typedef _Float16 v8h __attribute__((ext_vector_type(8)));
typedef float v4f __attribute__((ext_vector_type(4)));
typedef float v2f __attribute__((ext_vector_type(2)));

#if __has_builtin(__builtin_amdgcn_cvt_pk_f32_fp8) && __has_builtin(__builtin_amdgcn_cvt_pk_fp8_f32)
#define FP8_HW 1
#else
#define FP8_HW 0
#endif

// ---------------------------------------------------------------------------
// fp8 helpers (encode in gemm1/agg1-epilogue, decode in agg1/agg2 — matched)
// ---------------------------------------------------------------------------
__device__ __forceinline__ unsigned char f32_to_fp8(float v) {
#if FP8_HW
    int r = __builtin_amdgcn_cvt_pk_fp8_f32(v, v, 0, false);
    return (unsigned char)(r & 0xFF);
#else
    __half h = __float2half(v);
    unsigned short u; __builtin_memcpy(&u, &h, 2);
    int s = (u >> 15) << 7;
    int a = (u & 0x7FFF) + 0x40;
    if (a < (9 << 10)) return (unsigned char)s;
    int t = (a >> 7) - 64;
    if (t > 126) t = 126;
    return (unsigned char)(s | t);
#endif
}

__device__ __forceinline__ unsigned short f32x2_to_fp8x2(float v0, float v1) {
#if FP8_HW
    int r = __builtin_amdgcn_cvt_pk_fp8_f32(v0, v1, 0, false);
    return (unsigned short)(r & 0xFFFF);
#else
    return (unsigned short)(f32_to_fp8(v0) | (f32_to_fp8(v1) << 8));
#endif
}

__device__ __forceinline__ float2 fp8x2_to_f32(unsigned short w) {
#if FP8_HW
    v2f r = __builtin_amdgcn_cvt_pk_f32_fp8((int)w, false);
    return make_float2(r.x, r.y);
#else
    int b0 = w & 0xFF, b1 = w >> 8;
    unsigned short h0 = (unsigned short)((((b0 & 0x7F) + 64) << 7) | ((b0 & 0x80) << 8));
    unsigned short h1 = (unsigned short)((((b1 & 0x7F) + 64) << 7) | ((b1 & 0x80) << 8));
    __half x0, x1;
    __builtin_memcpy(&x0, &h0, 2);
    __builtin_memcpy(&x1, &h1, 2);
    return make_float2(__half2float(x0), __half2float(x1));
#endif
}

// ---------------------------------------------------------------------------
// Helpers
// ---------------------------------------------------------------------------
__device__ __forceinline__ int load_idx(const int* __restrict__ ei, int is64, int pos) {
    return is64 ? ei[(size_t)2 * pos] : ei[pos];
}

__device__ __forceinline__ int h2_as_int(__half2 h) {
    int w; __builtin_memcpy(&w, &h, 4); return w;
}
__device__ __forceinline__ __half2 int_as_h2(int w) {
    __half2 h; __builtin_memcpy(&h, &w, 4); return h;
}

// Detect int64 vs int32 edge_index; ALSO zeroes bcnt.
__global__ void detect_kernel(const int* __restrict__ ei, int* __restrict__ flag,
                              int* __restrict__ bcnt, int nbkt) {
    __shared__ int any_odd;
    if (threadIdx.x == 0) any_odd = 0;
    __syncthreads();
    for (int u = threadIdx.x; u < nbkt; u += 256) bcnt[u] = 0;
    if (ei[2 * threadIdx.x + 1] != 0) atomicOr(&any_odd, 1);
    __syncthreads();
    if (threadIdx.x == 0) *flag = any_odd ? 0 : 1;
}

// Bucket histogram: LDS-aggregated, 4096 edges/block.
__global__ __launch_bounds__(256) void bhist_kernel(
    const int* __restrict__ ei, const int* __restrict__ flag,
    int* __restrict__ bcnt, int E, int nbkt) {
    __shared__ int cnt[NBKT_MAX];
    int t = threadIdx.x;
    for (int u = t; u < nbkt; u += 256) cnt[u] = 0;
    __syncthreads();
    int is64 = *flag;
    int e0 = blockIdx.x * 4096;
#pragma unroll
    for (int i = 0; i < 16; ++i) {
        int e = e0 + i * 256 + t;
        if (e < E) atomicAdd(&cnt[load_idx(ei, is64, E + e) >> BKT_SHIFT], 1);
    }
    __syncthreads();
    for (int u = t; u < nbkt; u += 256)
        if (cnt[u]) atomicAdd(&bcnt[u], cnt[u]);
}

// Exclusive scan over bcnt[nbkt] (nbkt <= 512); also bbase[nbkt]=E, rowptr[N]=E.
__global__ void bscan_kernel(const int* __restrict__ bcnt, int* __restrict__ bbase,
                             int* __restrict__ bcursor, int* __restrict__ rowptrN,
                             int nbkt, int E) {
    __shared__ int s[512];
    int t = threadIdx.x;
    int v = (t < nbkt) ? bcnt[t] : 0;
    s[t] = v;
    __syncthreads();
    for (int o = 1; o < 512; o <<= 1) {
        int u = (t >= o) ? s[t - o] : 0;
        __syncthreads();
        s[t] += u;
        __syncthreads();
    }
    if (t < nbkt) { int ex = s[t] - v; bbase[t] = ex; bcursor[t] = ex; }
    if (t == 0) { bbase[nbkt] = E; *rowptrN = E; }
}

// ---------------------------------------------------------------------------
// Pass 1: bucket multisplit, 8192 edges per 1024-thread block, two-phase.
// ---------------------------------------------------------------------------
__global__ __launch_bounds__(1024) void pass1_kernel(
    const int* __restrict__ ei, const int* __restrict__ flag,
    const float2* __restrict__ ea, int* __restrict__ bcursor,
    int4* __restrict__ staging, int E, int nbkt) {
    __shared__ int lcnt[NBKT_MAX];
    __shared__ int lcur[NBKT_MAX];
    int t = threadIdx.x;
    if (t < nbkt) lcnt[t] = 0;
    __syncthreads();
    int is64 = *flag;
    int e0 = blockIdx.x * 8192;
    int eend = min(e0 + 8192, E);

    for (int e = e0 + t; e < eend; e += 1024)
        atomicAdd(&lcnt[load_idx(ei, is64, E + e) >> BKT_SHIFT], 1);
    __syncthreads();

    if (t < nbkt) {
        int c = lcnt[t];
        lcur[t] = c ? atomicAdd(&bcursor[t], c) : 0;
    }
    __syncthreads();

    for (int e = e0 + t; e < eend; e += 1024) {
        int src = load_idx(ei, is64, e);
        int dst = load_idx(ei, is64, E + e);
        float2 a = ea[e];
        int pos = atomicAdd(&lcur[dst >> BKT_SHIFT], 1);
        staging[pos] = make_int4(src, dst,
                                 __float_as_int(a.x), __float_as_int(a.y));
    }
}

// ---------------------------------------------------------------------------
// Pass 2: one block per bucket. Derives per-node rowptr; places records.
//   rec.x = src (plain)
// ---------------------------------------------------------------------------
__global__ __launch_bounds__(256) void pass2_kernel(
    const int4* __restrict__ staging, const int* __restrict__ bbase,
    const float* __restrict__ mu1, const float* __restrict__ sg1,
    const float* __restrict__ mu2, const float* __restrict__ sg2,
    int4* __restrict__ rec, int* __restrict__ rowptr, int N) {
    __shared__ int lcnt[BKT_SIZE];
    __shared__ int ssc[BKT_SIZE];
    __shared__ int lcur[BKT_SIZE];
    int b = blockIdx.x;
    int node0 = b << BKT_SHIFT;
    int t = threadIdx.x;
    int beg = bbase[b], end = bbase[b + 1];

    if (t < BKT_SIZE) lcnt[t] = 0;
    __syncthreads();
    for (int j = beg + t; j < end; j += 256)
        atomicAdd(&lcnt[staging[j].y & (BKT_SIZE - 1)], 1);
    __syncthreads();
    int v = (t < BKT_SIZE) ? lcnt[t] : 0;
    if (t < BKT_SIZE) ssc[t] = v;
    __syncthreads();
    for (int o = 1; o < BKT_SIZE; o <<= 1) {
        int u = (t < BKT_SIZE && t >= o) ? ssc[t - o] : 0;
        __syncthreads();
        if (t < BKT_SIZE) ssc[t] += u;
        __syncthreads();
    }
    if (t < BKT_SIZE) {
        int excl = beg + ssc[t] - v;
        lcur[t] = excl;
        if (node0 + t < N) rowptr[node0 + t] = excl;
    }
    __syncthreads();

    float m1x[3], m1y[3], i1x[3], i1y[3], m2x[3], m2y[3], i2x[3], i2y[3];
#pragma unroll
    for (int k = 0; k < 3; ++k) {
        m1x[k] = mu1[2 * k]; m1y[k] = mu1[2 * k + 1];
        float s0 = sg1[2 * k], s1 = sg1[2 * k + 1];
        i1x[k] = -0.5f / (EPS + s0 * s0); i1y[k] = -0.5f / (EPS + s1 * s1);
        m2x[k] = mu2[2 * k]; m2y[k] = mu2[2 * k + 1];
        s0 = sg2[2 * k]; s1 = sg2[2 * k + 1];
        i2x[k] = -0.5f / (EPS + s0 * s0); i2y[k] = -0.5f / (EPS + s1 * s1);
    }

    for (int j = beg + t; j < end; j += 256) {
        int4 p = staging[j];
        float ax = __int_as_float(p.z), ay = __int_as_float(p.w);
        float g1v[3], g2v[3];
#pragma unroll
        for (int k = 0; k < 3; ++k) {
            float d0 = ax - m1x[k], d1 = ay - m1y[k];
            g1v[k] = __expf(d0 * d0 * i1x[k] + d1 * d1 * i1y[k]);
            d0 = ax - m2x[k]; d1 = ay - m2y[k];
            g2v[k] = __expf(d0 * d0 * i2x[k] + d1 * d1 * i2y[k]);
        }
        int pos = atomicAdd(&lcur[p.y & (BKT_SIZE - 1)], 1);
        int4 r;
        r.x = p.x;
        r.y = h2_as_int(__floats2half2_rn(g1v[0], g1v[1]));
        r.z = h2_as_int(__floats2half2_rn(g1v[2], g2v[0]));
        r.w = h2_as_int(__floats2half2_rn(g2v[1], g2v[2]));
        rec[pos] = r;
    }
}

// ---------------------------------------------------------------------------
// Bprep: fragment-ordered fp16 copy of W = [g1 | r1]  (128 x 256).
// ---------------------------------------------------------------------------
__global__ void bprep_kernel(const float* __restrict__ g1, const float* __restrict__ r1,
                             __half* __restrict__ Bprep) {
    int gid = blockIdx.x * 256 + threadIdx.x;   // 32768 total
    if (gid >= 32768) return;
    int fi = gid >> 9;
    int lane = (gid >> 3) & 63;
    int i = gid & 7;
    int ks = fi & 3, cb = fi >> 2;
    int k = ks * 32 + (lane >> 4) * 8 + i;
    int c = cb * 16 + (lane & 15);
    float v = (c < 192) ? g1[k * 192 + c] : r1[k * 64 + (c - 192)];
    Bprep[gid] = __float2half(v);
}

// ---------------------------------------------------------------------------
// Layer-1 GEMM via MFMA f16: x [M,128] fp32 -> hw1k fp8 [M,192] + hw1r fp16 [M,64].
// ---------------------------------------------------------------------------
__global__ __launch_bounds__(256) void gemm1_mfma(
    const float* __restrict__ A, const __half* __restrict__ Bprep,
    unsigned char* __restrict__ hw1k, __half* __restrict__ hw1r, int M) {
    __shared__ char a_lds[64 * 256];   // 64 rows x 128 fp16, XOR-swizzled
    int row0 = blockIdx.x * 64;
    int tid = threadIdx.x;
    int wid = tid >> 6, lane = tid & 63;

    const float4* xf4 = reinterpret_cast<const float4*>(A);
#pragma unroll
    for (int j = 0; j < 8; ++j) {
        int g = j * 256 + tid;
        int r = g >> 5, c = g & 31;
        int gr = row0 + r;
        float4 f = (gr < M) ? xf4[(size_t)gr * 32 + c]
                            : make_float4(0.f, 0.f, 0.f, 0.f);
        int2 v;
        v.x = h2_as_int(__floats2half2_rn(f.x, f.y));
        v.y = h2_as_int(__floats2half2_rn(f.z, f.w));
        int byte = r * 256 + c * 8;
        byte ^= (r & 7) << 4;
        *reinterpret_cast<int2*>(&a_lds[byte]) = v;
    }

    v8h bf[2][4];   // [cf][ks]
#pragma unroll
    for (int cf = 0; cf < 2; ++cf)
#pragma unroll
        for (int ks = 0; ks < 4; ++ks) {
            int cb = blockIdx.y * 8 + wid * 2 + cf;
            int fi = cb * 4 + ks;
            bf[cf][ks] = *reinterpret_cast<const v8h*>(Bprep + (size_t)fi * 512 + lane * 8);
        }

    __syncthreads();

    v4f acc[4][2] = {};
#pragma unroll
    for (int ks = 0; ks < 4; ++ks) {
        v8h af[4];
#pragma unroll
        for (int rf = 0; rf < 4; ++rf) {
            int r = rf * 16 + (lane & 15);
            int byte = r * 256 + ks * 64 + (lane >> 4) * 16;
            byte ^= (r & 7) << 4;
            af[rf] = *reinterpret_cast<const v8h*>(&a_lds[byte]);
        }
#pragma unroll
        for (int rf = 0; rf < 4; ++rf)
#pragma unroll
            for (int cf = 0; cf < 2; ++cf)
                acc[rf][cf] = __builtin_amdgcn_mfma_f32_16x16x32_f16(
                    af[rf], bf[cf][ks], acc[rf][cf], 0, 0, 0);
    }

#pragma unroll
    for (int rf = 0; rf < 4; ++rf)
#pragma unroll
        for (int cf = 0; cf < 2; ++cf) {
            int gc = blockIdx.y * 128 + wid * 32 + cf * 16 + (lane & 15);
#pragma unroll
            for (int i = 0; i < 4; ++i) {
                int gr = row0 + rf * 16 + (lane >> 4) * 4 + i;
                if (gr < M) {
                    float val = acc[rf][cf][i];
                    if (gc < 192)
                        hw1k[(size_t)gr * 192 + gc] = f32_to_fp8(val);
                    else
                        hw1r[(size_t)gr * 64 + (gc - 192)] = __float2half(val);
                }
            }
        }
}

// ---------------------------------------------------------------------------
// agg1_fused v6: 32 lanes per node (wave = 2 nodes). Register-accumulated fp8
// gather (4-edge unrolled), ELU h2 -> per-wave LDS slot, matvec reads ONLY
// same-wave h2 -> NO post-gather __syncthreads (wave lockstep + lgkmcnt make
// same-wave LDS write->read safe). Single barrier after Wlds staging.
// -> hw2k fp8 (cols 0..47) + hw2r fp16 (cols 48..63).
// ---------------------------------------------------------------------------
__global__ __launch_bounds__(256) void agg1_fused(
    const int4* __restrict__ rec, const int* __restrict__ rowptr,
    const unsigned char* __restrict__ hw1k, const __half* __restrict__ hw1r,
    const float* __restrict__ b1, const float* __restrict__ g2,
    const float* __restrict__ r2, unsigned char* __restrict__ hw2k,
    __half* __restrict__ hw2r, int N) {
    __shared__ float Wlds[64][64];   // [k][c]: c<48 from g2, c>=48 from r2
    __shared__ float h2s[8][64];     // per half-wave slot (nl = (t>>5)&7)
    int t = threadIdx.x;

    for (int i = t; i < 4096; i += 256) {
        int k = i >> 6, c = i & 63;
        Wlds[k][c] = (c < 48) ? g2[k * 48 + c] : r2[k * 16 + (c - 48)];
    }
    __syncthreads();   // only barrier: Wlds visible to all before matvec

    int node = (blockIdx.x * 256 + t) >> 5;
    int nl = (t >> 5) & 7;
    int l = t & 31;
    bool active = node < N;

    float ax0 = 0.f, ay0 = 0.f, ax1 = 0.f, ay1 = 0.f;
    int beg = 0, end = 0;
    if (active) { beg = rowptr[node]; end = rowptr[node + 1]; }
    int j = beg;
    for (; j + 3 < end; j += 4) {
        int4 r0 = rec[j], r1 = rec[j + 1], r2v = rec[j + 2], r3 = rec[j + 3];
        const unsigned short* p0 = reinterpret_cast<const unsigned short*>(
            hw1k + (size_t)r0.x * 192);
        const unsigned short* p1 = reinterpret_cast<const unsigned short*>(
            hw1k + (size_t)r1.x * 192);
        const unsigned short* p2 = reinterpret_cast<const unsigned short*>(
            hw1k + (size_t)r2v.x * 192);
        const unsigned short* p3 = reinterpret_cast<const unsigned short*>(
            hw1k + (size_t)r3.x * 192);
        unsigned short w00 = p0[l], w01 = p0[32 + l], w02 = p0[64 + l];
        unsigned short w10 = p1[l], w11 = p1[32 + l], w12 = p1[64 + l];
        unsigned short w20 = p2[l], w21 = p2[32 + l], w22 = p2[64 + l];
        unsigned short w30 = p3[l], w31 = p3[32 + l], w32 = p3[64 + l];
        __half2 ha0 = int_as_h2(r0.y), hb0 = int_as_h2(r0.z);
        __half2 ha1 = int_as_h2(r1.y), hb1 = int_as_h2(r1.z);
        __half2 ha2 = int_as_h2(r2v.y), hb2 = int_as_h2(r2v.z);
        __half2 ha3 = int_as_h2(r3.y), hb3 = int_as_h2(r3.z);
        {
            float g0 = __low2float(ha0), g1 = __high2float(ha0), gg2 = __low2float(hb0);
            float2 a = fp8x2_to_f32(w00), b = fp8x2_to_f32(w01), c = fp8x2_to_f32(w02);
            ax0 += g0 * a.x + g1 * b.x + gg2 * c.x;
            ay0 += g0 * a.y + g1 * b.y + gg2 * c.y;
        }
        {
            float g0 = __low2float(ha1), g1 = __high2float(ha1), gg2 = __low2float(hb1);
            float2 a = fp8x2_to_f32(w10), b = fp8x2_to_f32(w11), c = fp8x2_to_f32(w12);
            ax1 += g0 * a.x + g1 * b.x + gg2 * c.x;
            ay1 += g0 * a.y + g1 * b.y + gg2 * c.y;
        }
        {
            float g0 = __low2float(ha2), g1 = __high2float(ha2), gg2 = __low2float(hb2);
            float2 a = fp8x2_to_f32(w20), b = fp8x2_to_f32(w21), c = fp8x2_to_f32(w22);
            ax0 += g0 * a.x + g1 * b.x + gg2 * c.x;
            ay0 += g0 * a.y + g1 * b.y + gg2 * c.y;
        }
        {
            float g0 = __low2float(ha3), g1 = __high2float(ha3), gg2 = __low2float(hb3);
            float2 a = fp8x2_to_f32(w30), b = fp8x2_to_f32(w31), c = fp8x2_to_f32(w32);
            ax1 += g0 * a.x + g1 * b.x + gg2 * c.x;
            ay1 += g0 * a.y + g1 * b.y + gg2 * c.y;
        }
    }
    for (; j < end; ++j) {
        int4 r0 = rec[j];
        __half2 ha0 = int_as_h2(r0.y), hb0 = int_as_h2(r0.z);
        float g0 = __low2float(ha0), g1 = __high2float(ha0), gg2 = __low2float(hb0);
        const unsigned short* p0 = reinterpret_cast<const unsigned short*>(
            hw1k + (size_t)r0.x * 192);
        float2 a = fp8x2_to_f32(p0[l]);
        float2 b = fp8x2_to_f32(p0[32 + l]);
        float2 c = fp8x2_to_f32(p0[64 + l]);
        ax0 += g0 * a.x + g1 * b.x + gg2 * c.x;
        ay0 += g0 * a.y + g1 * b.y + gg2 * c.y;
    }
    if (active) {
        float d = fmaxf((float)(end - beg), 1.0f);
        float2 root = __half22float2(
            reinterpret_cast<const __half2*>(hw1r + (size_t)node * 64)[l]);
        float2 bb = reinterpret_cast<const float2*>(b1)[l];
        float v0 = (ax0 + ax1) / d + root.x + bb.x;
        float v1 = (ay0 + ay1) / d + root.y + bb.y;
        h2s[nl][2 * l]     = v0 > 0.f ? v0 : expm1f(v0);
        h2s[nl][2 * l + 1] = v1 > 0.f ? v1 : expm1f(v1);
    }
    // NO __syncthreads: h2s[nl] written and read by the SAME wave only;
    // lgkmcnt ordering within the wave guarantees visibility.

    if (active) {
        float acc0 = 0.f, acc1 = 0.f;
#pragma unroll 8
        for (int k = 0; k < 64; ++k) {
            float hv = h2s[nl][k];                       // LDS broadcast
            float2 w = *reinterpret_cast<const float2*>(&Wlds[k][2 * l]);
            acc0 += hv * w.x;
            acc1 += hv * w.y;
        }
        int c0 = 2 * l;
        if (c0 < 48) {
            *reinterpret_cast<unsigned short*>(hw2k + (size_t)node * 48 + c0) =
                f32x2_to_fp8x2(acc0, acc1);
        } else {
            reinterpret_cast<__half2*>(hw2r + (size_t)node * 16)[l - 24] =
                __floats2half2_rn(acc0, acc1);
        }
    }
}

// ---------------------------------------------------------------------------
// agg2: 8 lanes per node, lane owns c = {2l, 2l+1}; fp8 gather table (48B row)
// + fp16 root. Fused mean+root+bias+log_softmax.
// ---------------------------------------------------------------------------
__global__ __launch_bounds__(256) void agg2_kernel(
    const int4* __restrict__ rec, const int* __restrict__ rowptr,
    const unsigned char* __restrict__ hw2k, const __half* __restrict__ hw2r,
    const float* __restrict__ b2, float* __restrict__ out, int N) {
    int node = (blockIdx.x * 256 + threadIdx.x) >> 3;
    int l = threadIdx.x & 7;
    if (node >= N) return;
    int beg = rowptr[node], end = rowptr[node + 1];
    float ax = 0.f, ay = 0.f;
    for (int j = beg; j < end; ++j) {
        int4 r = rec[j];
        __half2 hb = int_as_h2(r.z), hc = int_as_h2(r.w);
        float g0 = __high2float(hb), g1 = __low2float(hc), g2 = __high2float(hc);
        const unsigned short* p = reinterpret_cast<const unsigned short*>(
            hw2k + (size_t)r.x * 48);
        float2 f0 = fp8x2_to_f32(p[l]);
        float2 f1 = fp8x2_to_f32(p[8 + l]);
        float2 f2 = fp8x2_to_f32(p[16 + l]);
        ax += g0 * f0.x + g1 * f1.x + g2 * f2.x;
        ay += g0 * f0.y + g1 * f1.y + g2 * f2.y;
    }
    float d = fmaxf((float)(end - beg), 1.0f);
    float2 root = __half22float2(
        reinterpret_cast<const __half2*>(hw2r + (size_t)node * 16)[l]);
    float2 bb = reinterpret_cast<const float2*>(b2)[l];
    float v0 = ax / d + root.x + bb.x;
    float v1 = ay / d + root.y + bb.y;

    float mx = fmaxf(v0, v1);
#pragma unroll
    for (int off = 4; off >= 1; off >>= 1) mx = fmaxf(mx, __shfl_xor(mx, off, 8));
    float s = __expf(v0 - mx) + __expf(v1 - mx);
#pragma unroll
    for (int off = 4; off >= 1; off >>= 1) s += __shfl_xor(s, off, 8);
    float ls = __logf(s);
    float2 o = make_float2(v0 - mx - ls, v1 - mx - ls);
    reinterpret_cast<float2*>(out + (size_t)node * 16)[l] = o;
}

// ---------------------------------------------------------------------------
extern "C" void kernel_launch(void* const* d_in, const int* in_sizes, int n_in,
                              void* d_out, int out_size, void* d_ws, size_t ws_size,
                              hipStream_t stream) {
    const float* x   = (const float*)d_in[0];
    const int*   ei  = (const int*)d_in[1];
    const float* ea  = (const float*)d_in[2];
    const float* g1  = (const float*)d_in[3];
    const float* mu1 = (const float*)d_in[4];
    const float* sg1 = (const float*)d_in[5];
    const float* r1  = (const float*)d_in[6];
    const float* b1  = (const float*)d_in[7];
    const float* g2  = (const float*)d_in[8];
    const float* mu2 = (const float*)d_in[9];
    const float* sg2 = (const float*)d_in[10];
    const float* r2  = (const float*)d_in[11];
    const float* b2  = (const float*)d_in[12];

    const int N = in_sizes[0] / 128;   // 50000
    const int E = in_sizes[2] / 2;     // 800000
    const int nbkt = (N + BKT_SIZE - 1) >> BKT_SHIFT;   // 391

    // Workspace layout
    unsigned char* hw1k = (unsigned char*)d_ws;           // N*192 fp8 (9.6MB)
    __half* hw1r = (__half*)(hw1k + (size_t)N * 192);     // N*64 fp16
    unsigned char* hw2k = (unsigned char*)(hw1r + (size_t)N * 64);  // N*48 fp8
    __half* hw2r = (__half*)(hw2k + (size_t)N * 48);      // N*16 fp16
    int4*   rec  = (int4*)((char*)hw2r + (size_t)N * 32); // E int4 (12.8MB)
    int4*   staging = rec + E;                            // E int4 (12.8MB)
    __half* Bprep = (__half*)(staging + E);               // 32768 halves
    int*    rowptr  = (int*)(Bprep + 32768);              // N+1
    int*    bcnt    = rowptr + N + 1;                     // nbkt
    int*    bbase   = bcnt + nbkt;                        // nbkt+1
    int*    bcursor = bbase + nbkt + 1;                   // nbkt
    int*    flag    = bcursor + nbkt;                     // 1

    detect_kernel<<<1, 256, 0, stream>>>(ei, flag, bcnt, nbkt);
    bhist_kernel<<<(E + 4095) / 4096, 256, 0, stream>>>(ei, flag, bcnt, E, nbkt);
    bscan_kernel<<<1, 512, 0, stream>>>(bcnt, bbase, bcursor, rowptr + N, nbkt, E);

    pass1_kernel<<<(E + 8191) / 8192, 1024, 0, stream>>>(
        ei, flag, (const float2*)ea, bcursor, staging, E, nbkt);
    pass2_kernel<<<nbkt, 256, 0, stream>>>(
        staging, bbase, mu1, sg1, mu2, sg2, rec, rowptr, N);

    // Layer 1 GEMM (MFMA): x [N,128] @ [g1|root1] -> hw1k fp8 + hw1r fp16
    bprep_kernel<<<128, 256, 0, stream>>>(g1, r1, Bprep);
    gemm1_mfma<<<dim3((N + 63) / 64, 2), 256, 0, stream>>>(x, Bprep, hw1k, hw1r, N);

    // agg1 + layer-2 GEMM fused (same-wave matvec, no post-gather barrier)
    agg1_fused<<<((size_t)N * 32 + 255) / 256, 256, 0, stream>>>(
        rec, rowptr, hw1k, hw1r, b1, g2, r2, hw2k, hw2r, N);

    agg2_kernel<<<((size_t)N * 8 + 255) / 256, 256, 0, stream>>>(
        rec, rowptr, hw2k, hw2r, b2, (float*)d_out, N);
}